// Round 2
// baseline (15857.803 us; speedup 1.0000x reference)
//
#include <hip/hip_runtime.h>
#include <cmath>

#define VOCABN 32000
#define EE 128
#define HH 256
#define H3 768
#define HOPSN 3
#define HEADSN 4
#define NB 32
#define TMN 50
#define WLENN 20
#define TQN 20

#define NSLOTB 64   // persistent barrier-synced blocks for the slot GRU
#define JPB 4       // h-outputs per slot block (4*64 = 256)
#define NQB 32      // question blocks

// workspace offsets (floats)
#define OFF_WIHT_Q 0
#define OFF_WHHT_Q (OFF_WIHT_Q + EE*H3)
#define OFF_MEM    (OFF_WHHT_Q + HH*H3)
#define OFF_Q      (OFF_MEM + NB*TMN*HH)
#define OFF_OK     (OFF_Q + NB*HH)
#define OFF_WB     (OFF_OK + NB*HH)
#define OFF_REP    (OFF_WB + NB*HOPSN*HH)
#define OFF_G2     (OFF_REP + NB*HEADSN*HH)
#define OFF_REAS   (OFF_G2 + NB*9*H3)
#define OFF_HXG    (OFF_REAS + NB*H3)          // double-buffered h: [2][256][50]
#define OFF_SLOTS  (OFF_HXG + 2*HH*TMN)        // 64 slots, stride 32 u32 (128B)
#define WS_END     (OFF_SLOTS + NSLOTB*32)

__device__ __forceinline__ float sigm(float x) { return 1.f / (1.f + expf(-x)); }

// ---------------- K0: reset barrier slots + h exchange buffers (must run every launch) ---------
__global__ void k_init(float* __restrict__ ws)
{
    const int idx = blockIdx.x * blockDim.x + threadIdx.x;
    if (idx < 2*HH*TMN + NSLOTB*32) ws[OFF_HXG + idx] = 0.f;
}

// ---------------- K1: transpose question-GRU weights to [k][768] for coalesced streaming -------
__global__ void k_transpose(const float* __restrict__ qWih, const float* __restrict__ qWhh,
                            float* __restrict__ ws)
{
    float* WihT_q = ws + OFF_WIHT_Q;
    float* WhhT_q = ws + OFF_WHHT_Q;
    const int tid = blockIdx.x * blockDim.x + threadIdx.x;
    const int nt  = gridDim.x * blockDim.x;
    for (int idx = tid; idx < H3 * EE; idx += nt) {
        int j = idx / EE, e = idx % EE;
        WihT_q[e * H3 + j] = qWih[idx];
    }
    for (int idx = tid; idx < H3 * HH; idx += nt) {
        int j = idx / HH, k = idx % HH;
        WhhT_q[k * H3 + j] = qWhh[idx];
    }
}

// ---------------- K2: persistent GRU kernel --------------------------------------------------
// blocks 0..63  : slot GRU, weights-stationary in LDS, spin-barrier lockstep over 640 steps
// blocks 64..95 : question GRU, one chain each, streaming transposed weights (20 steps)
__global__ __launch_bounds__(256) void k_gru2(
    const int* __restrict__ stories, const int* __restrict__ questions,
    const float* __restrict__ emb,
    const float* __restrict__ iWih, const float* __restrict__ iWhh,
    const float* __restrict__ ibih, const float* __restrict__ ibhh,
    const float* __restrict__ qbih, const float* __restrict__ qbhh,
    float* __restrict__ ws)
{
    __shared__ float W_lds[12 * 384];     // 12 gate rows x (256 h | 128 x)
    __shared__ float red[16 * 4 * 64];    // partials: [slot16][wave4][lane64]
    __shared__ float qhs[HH];
    __shared__ float qxs[EE];
    const int tid = threadIdx.x;
    const int blk = blockIdx.x;

    if (blk < NSLOTB) {
        // ================= slot path =================
        const int J = blk * JPB;
        // stage this block's 12 gate rows into LDS once (rows rr: g=rr>>2, jj=rr&3)
        for (int idx = tid; idx < 12 * 384; idx += 256) {
            const int rr = idx / 384, k = idx - rr * 384;
            const int grow = ((rr >> 2) << 8) + J + (rr & 3);   // 256*g + J + jj
            W_lds[idx] = (k < HH) ? iWhh[grow * HH + k] : iWih[grow * EE + (k - HH)];
        }
        unsigned* __restrict__ slots = (unsigned*)(ws + OFF_SLOTS);
        float* __restrict__ hxg  = ws + OFF_HXG;    // [2][256][50]
        float* __restrict__ memv = ws + OFF_MEM;
        const int wv = tid >> 6, lane = tid & 63;
        const int c = (lane < TMN) ? lane : (TMN - 1);      // chain (memory slot)
        const int ejj = tid / TMN, ec = tid - ejj * TMN;    // epilogue mapping (tid<200)
        float br = 0.f, bz = 0.f, bnI = 0.f, bnH = 0.f;
        if (tid < 4 * TMN) {
            const int j = J + ejj;
            br  = ibih[j] + ibhh[j];
            bz  = ibih[HH + j] + ibhh[HH + j];
            bnI = ibih[2 * HH + j];
            bnH = ibhh[2 * HH + j];
        }
        __syncthreads();
        int sidx = 0;
        for (int n = 0; n < NB; ++n) {
            for (int t = 0; t < WLENN; ++t, ++sidx) {
                const int tok = stories[(n * TMN + c) * WLENN + t];
                const float* __restrict__ erow = emb + (size_t)tok * EE;
                float acc[16];
                #pragma unroll
                for (int r = 0; r < 16; ++r) acc[r] = 0.f;

                if (wv == 3) {
                    // x-part (gi): independent of h -> compute during barrier wait
                    for (int k = 0; k < EE; k += 4) {
                        const float4 xv = *reinterpret_cast<const float4*>(erow + k);
                        #pragma unroll
                        for (int rr = 0; rr < 12; ++rr) {
                            const float4 w4 = *reinterpret_cast<const float4*>(&W_lds[rr * 384 + HH + k]);
                            const int tgt = (rr < 8) ? rr : (rr + 4);  // n-gate gi kept separate
                            acc[tgt] = fmaf(xv.x, w4.x, fmaf(xv.y, w4.y,
                                       fmaf(xv.z, w4.z, fmaf(xv.w, w4.w, acc[tgt]))));
                        }
                    }
                } else if (wv == 0 && sidx > 0) {
                    // spin until every block finished step sidx-1 (lane b polls slot b)
                    unsigned* sl = slots + lane * 32;
                    const unsigned tgt = (unsigned)sidx;
                    while (__hip_atomic_load(sl, __ATOMIC_RELAXED, __HIP_MEMORY_SCOPE_AGENT) < tgt) {}
                    __threadfence();   // acquire: invalidate L1/L2 so h reads see L3-fresh data
                }
                __syncthreads();
                if (wv < 3) {
                    // h-part (gh): waves 0..2 split k = 0..255 as 88/84/84
                    const float* __restrict__ hb = hxg + (sidx & 1) * (HH * TMN);
                    const int k0 = (wv == 0) ? 0 : (wv == 1 ? 88 : 172);
                    const int k1 = (wv == 0) ? 88 : (wv == 1 ? 172 : 256);
                    for (int k = k0; k < k1; k += 4) {
                        const float h0 = hb[(k + 0) * TMN + c];
                        const float h1 = hb[(k + 1) * TMN + c];
                        const float h2 = hb[(k + 2) * TMN + c];
                        const float h3 = hb[(k + 3) * TMN + c];
                        #pragma unroll
                        for (int rr = 0; rr < 12; ++rr) {
                            const float4 w4 = *reinterpret_cast<const float4*>(&W_lds[rr * 384 + k]);
                            acc[rr] = fmaf(h0, w4.x, fmaf(h1, w4.y,
                                      fmaf(h2, w4.z, fmaf(h3, w4.w, acc[rr]))));
                        }
                    }
                }
                #pragma unroll
                for (int rr = 0; rr < 16; ++rr) red[(rr * 4 + wv) * 64 + lane] = acc[rr];
                __syncthreads();
                if (tid < 4 * TMN) {
                    float sr = 0.f, sz = 0.f, snh = 0.f, snx = 0.f;
                    #pragma unroll
                    for (int w = 0; w < 4; ++w) {
                        sr  += red[((ejj     ) * 4 + w) * 64 + ec];
                        sz  += red[((4 + ejj ) * 4 + w) * 64 + ec];
                        snh += red[((8 + ejj ) * 4 + w) * 64 + ec];
                        snx += red[((12 + ejj) * 4 + w) * 64 + ec];
                    }
                    const float r  = sigm(sr + br);
                    const float z  = sigm(sz + bz);
                    const float nn = tanhf((snx + bnI) + r * (snh + bnH));
                    const int hidx = (J + ejj) * TMN + ec;
                    const float hold = hxg[(sidx & 1) * (HH * TMN) + hidx];
                    const float hnew = (1.f - z) * nn + z * hold;
                    hxg[((sidx + 1) & 1) * (HH * TMN) + hidx] = hnew;
                    if (t == WLENN - 1) memv[(n * TMN + ec) * HH + J + ejj] = hnew;
                }
                __syncthreads();
                if (tid == 0) {
                    __threadfence();   // release: write h slice back past L2 before publishing
                    __hip_atomic_store(slots + blk * 32, (unsigned)(sidx + 1),
                                       __ATOMIC_RELAXED, __HIP_MEMORY_SCOPE_AGENT);
                }
            }
        }
    } else {
        // ================= question path (one chain per block, 20 steps) =================
        const int q = blk - NSLOTB;
        const int j = tid;
        const float* __restrict__ WihT = ws + OFF_WIHT_Q;  // [128][768]
        const float* __restrict__ WhhT = ws + OFF_WHHT_Q;  // [256][768]
        const float bR  = qbih[j] + qbhh[j];
        const float bZ  = qbih[HH + j] + qbhh[HH + j];
        const float bNI = qbih[2 * HH + j];
        const float bNH = qbhh[2 * HH + j];
        qhs[j] = 0.f;
        __syncthreads();
        for (int t = 0; t < TQN; ++t) {
            const int tok = questions[q * TQN + t];
            if (j < EE) qxs[j] = emb[(size_t)tok * EE + j];
            __syncthreads();
            float aR = 0.f, aZ = 0.f, aNx = 0.f;
            for (int k = 0; k < EE; ++k) {
                const float x = qxs[k];
                aR  = fmaf(x, WihT[k * H3 + j], aR);
                aZ  = fmaf(x, WihT[k * H3 + HH + j], aZ);
                aNx = fmaf(x, WihT[k * H3 + 2 * HH + j], aNx);
            }
            float hR = 0.f, hZ = 0.f, hNh = 0.f;
            for (int k = 0; k < HH; ++k) {
                const float hk = qhs[k];
                hR  = fmaf(hk, WhhT[k * H3 + j], hR);
                hZ  = fmaf(hk, WhhT[k * H3 + HH + j], hZ);
                hNh = fmaf(hk, WhhT[k * H3 + 2 * HH + j], hNh);
            }
            const float r  = sigm(aR + hR + bR);
            const float z  = sigm(aZ + hZ + bZ);
            const float nn = tanhf((aNx + bNI) + r * (hNh + bNH));
            const float hnew = (1.f - z) * nn + z * qhs[j];
            __syncthreads();
            qhs[j] = hnew;
        }
        __syncthreads();
        (ws + OFF_Q)[q * HH + j] = qhs[j];
    }
}

// ---------------- K3: ft(x) = relu(relu(x@W1.T+b1)@W2.T+b2), one block per row ----------------
__global__ __launch_bounds__(256) void k_ft(const float* __restrict__ src, float* __restrict__ dst,
                                            const float* __restrict__ W1, const float* __restrict__ b1,
                                            const float* __restrict__ W2, const float* __restrict__ b2)
{
    __shared__ float xr[HH];
    __shared__ float y1[HH];
    const int n = blockIdx.x, j = threadIdx.x;
    xr[j] = src[n * HH + j];
    __syncthreads();
    float acc = b1[j];
    const float4* w1 = reinterpret_cast<const float4*>(W1 + j * HH);
    #pragma unroll 4
    for (int k4 = 0; k4 < HH / 4; ++k4) {
        const float4 w = w1[k4];
        const float4 x = *reinterpret_cast<const float4*>(&xr[k4 * 4]);
        acc = fmaf(x.x, w.x, fmaf(x.y, w.y, fmaf(x.z, w.z, fmaf(x.w, w.w, acc))));
    }
    y1[j] = fmaxf(acc, 0.f);
    __syncthreads();
    acc = b2[j];
    const float4* w2 = reinterpret_cast<const float4*>(W2 + j * HH);
    #pragma unroll 4
    for (int k4 = 0; k4 < HH / 4; ++k4) {
        const float4 w = w2[k4];
        const float4 x = *reinterpret_cast<const float4*>(&y1[k4 * 4]);
        acc = fmaf(x.x, w.x, fmaf(x.y, w.y, fmaf(x.z, w.z, fmaf(x.w, w.w, acc))));
    }
    dst[n * HH + j] = fmaxf(acc, 0.f);
}

// ---------------- K4: attention scores + rep for one hop; block = (n, head) ----------------
__global__ __launch_bounds__(256) void k_attn(const float* __restrict__ Wm, float* __restrict__ ws, int hp)
{
    __shared__ float mem_s[TMN][HH];   // 51.2 KB
    __shared__ float ok_s[HH];
    __shared__ float wred[4][TMN];
    __shared__ float sc[TMN];
    const int n = blockIdx.x / HEADSN, hh = blockIdx.x % HEADSN;
    const int e = threadIdx.x;
    const float* __restrict__ memory = ws + OFF_MEM + n * TMN * HH;
    for (int idx = e; idx < TMN * HH; idx += HH)
        (&mem_s[0][0])[idx] = memory[idx];
    ok_s[e] = (ws + OFF_OK)[n * HH + e];
    __syncthreads();

    float p[TMN];
    #pragma unroll
    for (int t = 0; t < TMN; ++t) p[t] = 0.f;
    const float4* wrow = reinterpret_cast<const float4*>(Wm + ((size_t)(hp * HEADSN + hh) * HH + e) * HH);
    for (int d4 = 0; d4 < HH / 4; ++d4) {
        const float4 w = wrow[d4];
        #pragma unroll
        for (int t = 0; t < TMN; ++t) {
            const float4 m = *reinterpret_cast<const float4*>(&mem_s[t][d4 * 4]);
            p[t] = fmaf(m.x, w.x, fmaf(m.y, w.y, fmaf(m.z, w.z, fmaf(m.w, w.w, p[t]))));
        }
    }
    const float okv = ok_s[e];
    const int lane = e & 63, wv = e >> 6;
    #pragma unroll
    for (int t = 0; t < TMN; ++t) {
        float v = tanhf(p[t]) * okv;
        #pragma unroll
        for (int off = 32; off > 0; off >>= 1) v += __shfl_xor(v, off);
        if (lane == 0) wred[wv][t] = v;
    }
    __syncthreads();
    if (e < TMN) sc[e] = wred[0][e] + wred[1][e] + wred[2][e] + wred[3][e];
    __syncthreads();
    if (e == 0) {
        float mx = sc[0];
        for (int t = 1; t < TMN; ++t) mx = fmaxf(mx, sc[t]);
        float sum = 0.f;
        for (int t = 0; t < TMN; ++t) { const float ex = expf(sc[t] - mx); sc[t] = ex; sum += ex; }
        const float inv = 1.f / sum;
        for (int t = 0; t < TMN; ++t) sc[t] *= inv;
    }
    __syncthreads();
    float r = 0.f;
    #pragma unroll
    for (int t = 0; t < TMN; ++t) r = fmaf(sc[t], mem_s[t][e], r);
    (ws + OFF_REP)[(n * HEADSN + hh) * HH + e] = r;
}

// ---------------- K5: buf = rep_flat @ Wo_w.T + Wo_b; wb[n][hp]=buf; o_k = ft(buf) -------------
__global__ __launch_bounds__(256) void k_buf(const float* __restrict__ Wo_w, const float* __restrict__ Wo_b,
                                             const float* __restrict__ W1, const float* __restrict__ b1,
                                             const float* __restrict__ W2, const float* __restrict__ b2,
                                             float* __restrict__ ws, int hp)
{
    __shared__ float repf[HEADSN * HH];
    __shared__ float bufs[HH];
    __shared__ float y1[HH];
    const int n = blockIdx.x, j = threadIdx.x;
    const float* __restrict__ rep = ws + OFF_REP + n * HEADSN * HH;
    for (int idx = j; idx < HEADSN * HH; idx += HH) repf[idx] = rep[idx];
    __syncthreads();
    float acc = Wo_b[hp * HH + j];
    const float4* wrow = reinterpret_cast<const float4*>(Wo_w + ((size_t)hp * HH + j) * (HEADSN * HH));
    #pragma unroll 4
    for (int c4 = 0; c4 < HEADSN * HH / 4; ++c4) {
        const float4 w = wrow[c4];
        const float4 x = *reinterpret_cast<const float4*>(&repf[c4 * 4]);
        acc = fmaf(x.x, w.x, fmaf(x.y, w.y, fmaf(x.z, w.z, fmaf(x.w, w.w, acc))));
    }
    (ws + OFF_WB)[(n * HOPSN + hp) * HH + j] = acc;
    bufs[j] = acc;
    __syncthreads();
    float a1 = b1[j];
    const float4* w1 = reinterpret_cast<const float4*>(W1 + j * HH);
    #pragma unroll 4
    for (int k4 = 0; k4 < HH / 4; ++k4) {
        const float4 w = w1[k4];
        const float4 x = *reinterpret_cast<const float4*>(&bufs[k4 * 4]);
        a1 = fmaf(x.x, w.x, fmaf(x.y, w.y, fmaf(x.z, w.z, fmaf(x.w, w.w, a1))));
    }
    y1[j] = fmaxf(a1, 0.f);
    __syncthreads();
    float a2 = b2[j];
    const float4* w2 = reinterpret_cast<const float4*>(W2 + j * HH);
    #pragma unroll 4
    for (int k4 = 0; k4 < HH / 4; ++k4) {
        const float4 w = w2[k4];
        const float4 x = *reinterpret_cast<const float4*>(&y1[k4 * 4]);
        a2 = fmaf(x.x, w.x, fmaf(x.y, w.y, fmaf(x.z, w.z, fmaf(x.w, w.w, a2))));
    }
    (ws + OFF_OK)[n * HH + j] = fmaxf(a2, 0.f);
}

// ---------------- K6: relation MLP for one (n, pair) ----------------
__global__ __launch_bounds__(768) void k_rm(const float* __restrict__ gW1, const float* __restrict__ gb1,
                                            const float* __restrict__ gW2, const float* __restrict__ gb2,
                                            float* __restrict__ ws)
{
    __shared__ float comb[H3];
    __shared__ float y1[H3];
    const int n = blockIdx.x / 9, p = blockIdx.x % 9;
    const int ii = p / 3, jj = p % 3;
    const int tid = threadIdx.x;
    const float* __restrict__ wb = ws + OFF_WB + n * HOPSN * HH;
    const float* __restrict__ qv = ws + OFF_Q + n * HH;
    if (tid < HH)           comb[tid] = wb[jj * HH + tid];
    else if (tid < 2 * HH)  comb[tid] = wb[ii * HH + (tid - HH)];
    else                    comb[tid] = qv[tid - 2 * HH];
    __syncthreads();
    float acc = gb1[tid];
    const float4* w1 = reinterpret_cast<const float4*>(gW1 + (size_t)tid * H3);
    #pragma unroll 4
    for (int c4 = 0; c4 < H3 / 4; ++c4) {
        const float4 w = w1[c4];
        const float4 x = *reinterpret_cast<const float4*>(&comb[c4 * 4]);
        acc = fmaf(x.x, w.x, fmaf(x.y, w.y, fmaf(x.z, w.z, fmaf(x.w, w.w, acc))));
    }
    y1[tid] = fmaxf(acc, 0.f);
    __syncthreads();
    acc = gb2[tid];
    const float4* w2 = reinterpret_cast<const float4*>(gW2 + (size_t)tid * H3);
    #pragma unroll 4
    for (int c4 = 0; c4 < H3 / 4; ++c4) {
        const float4 w = w2[c4];
        const float4 x = *reinterpret_cast<const float4*>(&y1[c4 * 4]);
        acc = fmaf(x.x, w.x, fmaf(x.y, w.y, fmaf(x.z, w.z, fmaf(x.w, w.w, acc))));
    }
    (ws + OFF_G2)[((size_t)n * 9 + p) * H3 + tid] = fmaxf(acc, 0.f);
}

// ---------------- K7: reasoning = sum over 9 pairs ----------------
__global__ void k_reduce(float* __restrict__ ws)
{
    const int idx = blockIdx.x * blockDim.x + threadIdx.x;
    if (idx >= NB * H3) return;
    const int n = idx / H3, d = idx % H3;
    const float* __restrict__ g2 = ws + OFF_G2 + (size_t)n * 9 * H3 + d;
    float s = 0.f;
    #pragma unroll
    for (int p = 0; p < 9; ++p) s += g2[p * H3];
    (ws + OFF_REAS)[idx] = s;
}

// ---------------- K8: out = reasoning @ V_w.T ----------------
__global__ __launch_bounds__(256) void k_out(const float* __restrict__ V_w, const float* __restrict__ ws,
                                             float* __restrict__ out)
{
    __shared__ float rs[NB * H3];
    const int v = blockIdx.x * 256 + threadIdx.x;
    for (int idx = threadIdx.x; idx < NB * H3; idx += 256) rs[idx] = (ws + OFF_REAS)[idx];
    __syncthreads();
    float acc[NB];
    #pragma unroll
    for (int nn = 0; nn < NB; ++nn) acc[nn] = 0.f;
    const float4* vw = reinterpret_cast<const float4*>(V_w + (size_t)v * H3);
    for (int d4 = 0; d4 < H3 / 4; ++d4) {
        const float4 w = vw[d4];
        #pragma unroll
        for (int nn = 0; nn < NB; ++nn) {
            const float4 r = *reinterpret_cast<const float4*>(&rs[nn * H3 + d4 * 4]);
            acc[nn] = fmaf(r.x, w.x, fmaf(r.y, w.y, fmaf(r.z, w.z, fmaf(r.w, w.w, acc[nn]))));
        }
    }
    #pragma unroll
    for (int nn = 0; nn < NB; ++nn) out[(size_t)nn * VOCABN + v] = acc[nn];
}

extern "C" void kernel_launch(void* const* d_in, const int* in_sizes, int n_in,
                              void* d_out, int out_size, void* d_ws, size_t ws_size,
                              hipStream_t stream)
{
    const int*   stories   = (const int*)d_in[0];
    const int*   questions = (const int*)d_in[1];
    const float* emb   = (const float*)d_in[2];
    const float* qWih  = (const float*)d_in[3];
    const float* qWhh  = (const float*)d_in[4];
    const float* qbih  = (const float*)d_in[5];
    const float* qbhh  = (const float*)d_in[6];
    const float* iWih  = (const float*)d_in[7];
    const float* iWhh  = (const float*)d_in[8];
    const float* ibih  = (const float*)d_in[9];
    const float* ibhh  = (const float*)d_in[10];
    const float* Wm    = (const float*)d_in[11];
    const float* Wo_w  = (const float*)d_in[12];
    const float* Wo_b  = (const float*)d_in[13];
    const float* ftW1  = (const float*)d_in[14];
    const float* ftb1  = (const float*)d_in[15];
    const float* ftW2  = (const float*)d_in[16];
    const float* ftb2  = (const float*)d_in[17];
    const float* gW1   = (const float*)d_in[18];
    const float* gb1   = (const float*)d_in[19];
    const float* gW2   = (const float*)d_in[20];
    const float* gb2   = (const float*)d_in[21];
    const float* V_w   = (const float*)d_in[22];
    float* ws  = (float*)d_ws;
    float* out = (float*)d_out;

    hipLaunchKernelGGL(k_init, dim3((2*HH*TMN + NSLOTB*32 + 255) / 256), dim3(256), 0, stream, ws);
    hipLaunchKernelGGL(k_transpose, dim3(128), dim3(256), 0, stream, qWih, qWhh, ws);
    hipLaunchKernelGGL(k_gru2, dim3(NSLOTB + NQB), dim3(256), 0, stream,
                       stories, questions, emb, iWih, iWhh, ibih, ibhh, qbih, qbhh, ws);
    hipLaunchKernelGGL(k_ft, dim3(NB), dim3(HH), 0, stream, ws + OFF_Q, ws + OFF_OK, ftW1, ftb1, ftW2, ftb2);
    for (int hp = 0; hp < HOPSN; ++hp) {
        hipLaunchKernelGGL(k_attn, dim3(NB * HEADSN), dim3(HH), 0, stream, Wm, ws, hp);
        hipLaunchKernelGGL(k_buf, dim3(NB), dim3(HH), 0, stream, Wo_w, Wo_b, ftW1, ftb1, ftW2, ftb2, ws, hp);
    }
    hipLaunchKernelGGL(k_rm, dim3(NB * 9), dim3(H3), 0, stream, gW1, gb1, gW2, gb2, ws);
    hipLaunchKernelGGL(k_reduce, dim3((NB * H3 + 255) / 256), dim3(256), 0, stream, ws);
    hipLaunchKernelGGL(k_out, dim3(VOCABN / 256), dim3(256), 0, stream, V_w, ws, out);
}

// Round 3
// 7843.695 us; speedup vs baseline: 2.0217x; 2.0217x over previous
//
#include <hip/hip_runtime.h>
#include <cmath>

#define VOCABN 32000
#define EE 128
#define HH 256
#define H3 768
#define HOPSN 3
#define HEADSN 4
#define NB 32
#define TMN 50
#define WLENN 20
#define TQN 20
#define NPOS (NB*TMN*WLENN)   // 32000 story token positions

// workspace offsets (floats)
#define OFF_WIHT_Q 0
#define OFF_WHHT_Q (OFF_WIHT_Q + EE*H3)
#define OFF_MEM    (OFF_WHHT_Q + HH*H3)
#define OFF_Q      (OFF_MEM + NB*TMN*HH)
#define OFF_OK     (OFF_Q + NB*HH)
#define OFF_WB     (OFF_OK + NB*HH)
#define OFF_REP    (OFF_WB + NB*HOPSN*HH)
#define OFF_REAS   (OFF_REP + NB*HEADSN*HH)
#define OFF_GI     (OFF_REAS + NB*H3)          // ushort[NPOS*768] -> NPOS*H3/2 floats

__device__ __forceinline__ float sigm(float x) { return 1.f / (1.f + expf(-x)); }
__device__ __forceinline__ unsigned f2bf(float f) {       // f32 -> bf16 bits (RNE)
    unsigned u = __float_as_uint(f);
    return (u + 0x7fffu + ((u >> 16) & 1u)) >> 16;
}
__device__ __forceinline__ float bflo(unsigned w) { return __uint_as_float(w << 16); }
__device__ __forceinline__ float bfhi(unsigned w) { return __uint_as_float(w & 0xffff0000u); }

// ---------------- K1: transpose question-GRU weights to [k][768] ----------------
__global__ void k_transpose(const float* __restrict__ qWih, const float* __restrict__ qWhh,
                            float* __restrict__ ws)
{
    float* WihT_q = ws + OFF_WIHT_Q;
    float* WhhT_q = ws + OFF_WHHT_Q;
    const int tid = blockIdx.x * blockDim.x + threadIdx.x;
    const int nt  = gridDim.x * blockDim.x;
    for (int idx = tid; idx < H3 * EE; idx += nt) {
        int j = idx / EE, e = idx % EE;
        WihT_q[e * H3 + j] = qWih[idx];
    }
    for (int idx = tid; idx < H3 * HH; idx += nt) {
        int j = idx / HH, k = idx % HH;
        WhhT_q[k * H3 + j] = qWhh[idx];
    }
}

// ---------------- K2: gi = emb[tok] @ iWih.T for all 32000 story positions (bf16 out) ----------
#define GIP 64
__global__ __launch_bounds__(768) void k_gi(const int* __restrict__ stories,
                                            const float* __restrict__ emb,
                                            const float* __restrict__ iWih,
                                            float* __restrict__ ws)
{
    __shared__ float xe[GIP][EE];   // 32 KB
    unsigned short* gi = (unsigned short*)(ws + OFF_GI);
    const int j = threadIdx.x;
    const int p0 = blockIdx.x * GIP;
    // Wih row j as packed bf16 in 64 VGPRs
    unsigned wr[EE / 2];
    #pragma unroll
    for (int c = 0; c < EE / 2; ++c) {
        const float2 w2 = *reinterpret_cast<const float2*>(iWih + (size_t)j * EE + 2 * c);
        wr[c] = f2bf(w2.x) | (f2bf(w2.y) << 16);
    }
    for (int idx = j; idx < GIP * EE; idx += H3) {
        const int p = idx >> 7, e = idx & 127;
        const int tok = stories[p0 + p];
        xe[p][e] = emb[(size_t)tok * EE + e];
    }
    __syncthreads();
    for (int p = 0; p < GIP; ++p) {
        float acc = 0.f;
        #pragma unroll
        for (int c = 0; c < EE / 2; ++c) {
            const unsigned w = wr[c];
            acc = fmaf(xe[p][2 * c], bflo(w), fmaf(xe[p][2 * c + 1], bfhi(w), acc));
        }
        gi[(size_t)(p0 + p) * H3 + j] = (unsigned short)f2bf(acc);
    }
}

// ---------------- K3: recurrent GRUs, no cross-block sync ----------------
// blocks 0..49  : slot chains, Whh register-resident (bf16), gi precomputed
// blocks 50..81 : question chains, streamed transposed weights
__global__ __launch_bounds__(512, 1) void k_gru3(
    const int* __restrict__ stories, const int* __restrict__ questions,
    const float* __restrict__ emb,
    const float* __restrict__ iWhh,
    const float* __restrict__ ibih, const float* __restrict__ ibhh,
    const float* __restrict__ qbih, const float* __restrict__ qbhh,
    float* __restrict__ ws)
{
    __shared__ float hs[HH];
    __shared__ float red[HH][5];   // stride-5: conflict-light partial exchange
    __shared__ float xs[EE];
    const int tid = threadIdx.x;
    const int blk = blockIdx.x;
    const int j = tid & 255, kh = tid >> 8;   // output index, k-half

    if (blk < TMN) {
        // ================= slot path: weights in registers =================
        const int c = blk;
        unsigned wr_[64], wz_[64], wn_[64];
        {
            const float* br_ = iWhh + (size_t)j * HH + kh * 128;
            const float* bz_ = iWhh + (size_t)(HH + j) * HH + kh * 128;
            const float* bn_ = iWhh + (size_t)(2 * HH + j) * HH + kh * 128;
            #pragma unroll
            for (int c2 = 0; c2 < 64; ++c2) {
                const float2 a = *reinterpret_cast<const float2*>(br_ + 2 * c2);
                wr_[c2] = f2bf(a.x) | (f2bf(a.y) << 16);
            }
            #pragma unroll
            for (int c2 = 0; c2 < 64; ++c2) {
                const float2 a = *reinterpret_cast<const float2*>(bz_ + 2 * c2);
                wz_[c2] = f2bf(a.x) | (f2bf(a.y) << 16);
            }
            #pragma unroll
            for (int c2 = 0; c2 < 64; ++c2) {
                const float2 a = *reinterpret_cast<const float2*>(bn_ + 2 * c2);
                wn_[c2] = f2bf(a.x) | (f2bf(a.y) << 16);
            }
        }
        float br = 0.f, bz = 0.f, bnI = 0.f, bnH = 0.f;
        if (kh == 0) {
            br  = ibih[j] + ibhh[j];
            bz  = ibih[HH + j] + ibhh[HH + j];
            bnI = ibih[2 * HH + j];
            bnH = ibhh[2 * HH + j];
        }
        if (tid < HH) hs[tid] = 0.f;
        const unsigned short* __restrict__ gi = (const unsigned short*)(ws + OFF_GI);
        float* __restrict__ memv = ws + OFF_MEM;
        __syncthreads();
        for (int n = 0; n < NB; ++n) {
            for (int t = 0; t < WLENN; ++t) {
                float gir = 0.f, giz = 0.f, gin = 0.f;
                if (kh == 0) {   // issue early; consumed after FMA loop
                    const size_t gb = (size_t)((n * TMN + c) * WLENN + t) * H3;
                    gir = __uint_as_float((unsigned)gi[gb + j] << 16);
                    giz = __uint_as_float((unsigned)gi[gb + HH + j] << 16);
                    gin = __uint_as_float((unsigned)gi[gb + 2 * HH + j] << 16);
                }
                float ar = 0.f, az = 0.f, an = 0.f;
                const float4* h4 = reinterpret_cast<const float4*>(&hs[kh * 128]);
                #pragma unroll
                for (int q = 0; q < 32; ++q) {
                    const float4 h = h4[q];
                    const unsigned wr0 = wr_[2 * q], wr1 = wr_[2 * q + 1];
                    ar = fmaf(h.x, bflo(wr0), fmaf(h.y, bfhi(wr0), ar));
                    ar = fmaf(h.z, bflo(wr1), fmaf(h.w, bfhi(wr1), ar));
                    const unsigned wz0 = wz_[2 * q], wz1 = wz_[2 * q + 1];
                    az = fmaf(h.x, bflo(wz0), fmaf(h.y, bfhi(wz0), az));
                    az = fmaf(h.z, bflo(wz1), fmaf(h.w, bfhi(wz1), az));
                    const unsigned wn0 = wn_[2 * q], wn1 = wn_[2 * q + 1];
                    an = fmaf(h.x, bflo(wn0), fmaf(h.y, bfhi(wn0), an));
                    an = fmaf(h.z, bflo(wn1), fmaf(h.w, bfhi(wn1), an));
                }
                if (kh == 1) { red[j][0] = ar; red[j][1] = az; red[j][2] = an; }
                __syncthreads();
                if (kh == 0) {
                    const float r  = sigm(ar + red[j][0] + gir + br);
                    const float z  = sigm(az + red[j][1] + giz + bz);
                    const float nn = tanhf((gin + bnI) + r * (an + red[j][2] + bnH));
                    const float hnew = (1.f - z) * nn + z * hs[j];
                    hs[j] = hnew;
                    if (t == WLENN - 1) memv[(size_t)(n * TMN + c) * HH + j] = hnew;
                }
                __syncthreads();
            }
        }
    } else {
        // ================= question path: streamed weights, 20 steps =================
        const int qn = blk - TMN;
        const float* __restrict__ WihT = ws + OFF_WIHT_Q;   // [128][768]
        const float* __restrict__ WhhT = ws + OFF_WHHT_Q;   // [256][768]
        float br = 0.f, bz = 0.f, bnI = 0.f, bnH = 0.f;
        if (kh == 0) {
            br  = qbih[j] + qbhh[j];
            bz  = qbih[HH + j] + qbhh[HH + j];
            bnI = qbih[2 * HH + j];
            bnH = qbhh[2 * HH + j];
        }
        if (tid < HH) hs[tid] = 0.f;
        __syncthreads();
        for (int t = 0; t < TQN; ++t) {
            const int tok = questions[qn * TQN + t];
            if (tid < EE) xs[tid] = emb[(size_t)tok * EE + tid];
            __syncthreads();
            float ar = 0.f, az = 0.f, anx = 0.f, anh = 0.f;
            for (int k = kh * 64; k < kh * 64 + 64; ++k) {
                const float x = xs[k];
                ar  = fmaf(x, WihT[k * H3 + j], ar);
                az  = fmaf(x, WihT[k * H3 + HH + j], az);
                anx = fmaf(x, WihT[k * H3 + 2 * HH + j], anx);
            }
            for (int k = kh * 128; k < kh * 128 + 128; ++k) {
                const float h = hs[k];
                ar  = fmaf(h, WhhT[k * H3 + j], ar);
                az  = fmaf(h, WhhT[k * H3 + HH + j], az);
                anh = fmaf(h, WhhT[k * H3 + 2 * HH + j], anh);
            }
            if (kh == 1) { red[j][0] = ar; red[j][1] = az; red[j][2] = anx; red[j][3] = anh; }
            __syncthreads();
            if (kh == 0) {
                const float r  = sigm(ar + red[j][0] + br);
                const float z  = sigm(az + red[j][1] + bz);
                const float nn = tanhf((anx + red[j][2] + bnI) + r * (anh + red[j][3] + bnH));
                hs[j] = (1.f - z) * nn + z * hs[j];
            }
            __syncthreads();
        }
        if (kh == 0) (ws + OFF_Q)[qn * HH + j] = hs[j];
    }
}

// ---------------- K4: ft(x), one block per row ----------------
__global__ __launch_bounds__(256) void k_ft(const float* __restrict__ src, float* __restrict__ dst,
                                            const float* __restrict__ W1, const float* __restrict__ b1,
                                            const float* __restrict__ W2, const float* __restrict__ b2)
{
    __shared__ float xr[HH];
    __shared__ float y1[HH];
    const int n = blockIdx.x, j = threadIdx.x;
    xr[j] = src[n * HH + j];
    __syncthreads();
    float acc = b1[j];
    const float4* w1 = reinterpret_cast<const float4*>(W1 + j * HH);
    #pragma unroll 4
    for (int k4 = 0; k4 < HH / 4; ++k4) {
        const float4 w = w1[k4];
        const float4 x = *reinterpret_cast<const float4*>(&xr[k4 * 4]);
        acc = fmaf(x.x, w.x, fmaf(x.y, w.y, fmaf(x.z, w.z, fmaf(x.w, w.w, acc))));
    }
    y1[j] = fmaxf(acc, 0.f);
    __syncthreads();
    acc = b2[j];
    const float4* w2 = reinterpret_cast<const float4*>(W2 + j * HH);
    #pragma unroll 4
    for (int k4 = 0; k4 < HH / 4; ++k4) {
        const float4 w = w2[k4];
        const float4 x = *reinterpret_cast<const float4*>(&y1[k4 * 4]);
        acc = fmaf(x.x, w.x, fmaf(x.y, w.y, fmaf(x.z, w.z, fmaf(x.w, w.w, acc))));
    }
    dst[n * HH + j] = fmaxf(acc, 0.f);
}

// ---------------- K5: attention scores + rep for one hop; block = (n, head) ----------------
__global__ __launch_bounds__(256) void k_attn(const float* __restrict__ Wm, float* __restrict__ ws, int hp)
{
    __shared__ float mem_s[TMN][HH];
    __shared__ float ok_s[HH];
    __shared__ float wred[4][TMN];
    __shared__ float sc[TMN];
    const int n = blockIdx.x / HEADSN, hh = blockIdx.x % HEADSN;
    const int e = threadIdx.x;
    const float* __restrict__ memory = ws + OFF_MEM + n * TMN * HH;
    for (int idx = e; idx < TMN * HH; idx += HH)
        (&mem_s[0][0])[idx] = memory[idx];
    ok_s[e] = (ws + OFF_OK)[n * HH + e];
    __syncthreads();

    float p[TMN];
    #pragma unroll
    for (int t = 0; t < TMN; ++t) p[t] = 0.f;
    const float4* wrow = reinterpret_cast<const float4*>(Wm + ((size_t)(hp * HEADSN + hh) * HH + e) * HH);
    for (int d4 = 0; d4 < HH / 4; ++d4) {
        const float4 w = wrow[d4];
        #pragma unroll
        for (int t = 0; t < TMN; ++t) {
            const float4 m = *reinterpret_cast<const float4*>(&mem_s[t][d4 * 4]);
            p[t] = fmaf(m.x, w.x, fmaf(m.y, w.y, fmaf(m.z, w.z, fmaf(m.w, w.w, p[t]))));
        }
    }
    const float okv = ok_s[e];
    const int lane = e & 63, wv = e >> 6;
    #pragma unroll
    for (int t = 0; t < TMN; ++t) {
        float v = tanhf(p[t]) * okv;
        #pragma unroll
        for (int off = 32; off > 0; off >>= 1) v += __shfl_xor(v, off);
        if (lane == 0) wred[wv][t] = v;
    }
    __syncthreads();
    if (e < TMN) sc[e] = wred[0][e] + wred[1][e] + wred[2][e] + wred[3][e];
    __syncthreads();
    if (e == 0) {
        float mx = sc[0];
        for (int t = 1; t < TMN; ++t) mx = fmaxf(mx, sc[t]);
        float sum = 0.f;
        for (int t = 0; t < TMN; ++t) { const float ex = expf(sc[t] - mx); sc[t] = ex; sum += ex; }
        const float inv = 1.f / sum;
        for (int t = 0; t < TMN; ++t) sc[t] *= inv;
    }
    __syncthreads();
    float r = 0.f;
    #pragma unroll
    for (int t = 0; t < TMN; ++t) r = fmaf(sc[t], mem_s[t][e], r);
    (ws + OFF_REP)[(n * HEADSN + hh) * HH + e] = r;
}

// ---------------- K6: buf = rep @ Wo_w.T + Wo_b; o_k = ft(buf) ----------------
__global__ __launch_bounds__(256) void k_buf(const float* __restrict__ Wo_w, const float* __restrict__ Wo_b,
                                             const float* __restrict__ W1, const float* __restrict__ b1,
                                             const float* __restrict__ W2, const float* __restrict__ b2,
                                             float* __restrict__ ws, int hp)
{
    __shared__ float repf[HEADSN * HH];
    __shared__ float bufs[HH];
    __shared__ float y1[HH];
    const int n = blockIdx.x, j = threadIdx.x;
    const float* __restrict__ rep = ws + OFF_REP + n * HEADSN * HH;
    for (int idx = j; idx < HEADSN * HH; idx += HH) repf[idx] = rep[idx];
    __syncthreads();
    float acc = Wo_b[hp * HH + j];
    const float4* wrow = reinterpret_cast<const float4*>(Wo_w + ((size_t)hp * HH + j) * (HEADSN * HH));
    #pragma unroll 4
    for (int c4 = 0; c4 < HEADSN * HH / 4; ++c4) {
        const float4 w = wrow[c4];
        const float4 x = *reinterpret_cast<const float4*>(&repf[c4 * 4]);
        acc = fmaf(x.x, w.x, fmaf(x.y, w.y, fmaf(x.z, w.z, fmaf(x.w, w.w, acc))));
    }
    (ws + OFF_WB)[(n * HOPSN + hp) * HH + j] = acc;
    bufs[j] = acc;
    __syncthreads();
    float a1 = b1[j];
    const float4* w1 = reinterpret_cast<const float4*>(W1 + j * HH);
    #pragma unroll 4
    for (int k4 = 0; k4 < HH / 4; ++k4) {
        const float4 w = w1[k4];
        const float4 x = *reinterpret_cast<const float4*>(&bufs[k4 * 4]);
        a1 = fmaf(x.x, w.x, fmaf(x.y, w.y, fmaf(x.z, w.z, fmaf(x.w, w.w, a1))));
    }
    y1[j] = fmaxf(a1, 0.f);
    __syncthreads();
    float a2 = b2[j];
    const float4* w2 = reinterpret_cast<const float4*>(W2 + j * HH);
    #pragma unroll 4
    for (int k4 = 0; k4 < HH / 4; ++k4) {
        const float4 w = w2[k4];
        const float4 x = *reinterpret_cast<const float4*>(&y1[k4 * 4]);
        a2 = fmaf(x.x, w.x, fmaf(x.y, w.y, fmaf(x.z, w.z, fmaf(x.w, w.w, a2))));
    }
    (ws + OFF_OK)[n * HH + j] = fmaxf(a2, 0.f);
}

// ---------------- K7: relation MLP, one block per n; sums 9 pairs into REAS ----------------
__global__ __launch_bounds__(768) void k_rm(const float* __restrict__ gW1, const float* __restrict__ gb1,
                                            const float* __restrict__ gW2, const float* __restrict__ gb2,
                                            float* __restrict__ ws)
{
    __shared__ float comb[9][H3];   // 27.6 KB
    __shared__ float y1[9][H3];     // 27.6 KB
    const int n = blockIdx.x;
    const int o = threadIdx.x;
    const float* __restrict__ wb = ws + OFF_WB + n * HOPSN * HH;
    const float* __restrict__ qv = ws + OFF_Q + n * HH;
    #pragma unroll
    for (int p = 0; p < 9; ++p) {
        const int ii = p / 3, jj = p % 3;
        float v;
        if (o < HH)            v = wb[jj * HH + o];
        else if (o < 2 * HH)   v = wb[ii * HH + (o - HH)];
        else                   v = qv[o - 2 * HH];
        comb[p][o] = v;
    }
    __syncthreads();
    float acc[9];
    #pragma unroll
    for (int p = 0; p < 9; ++p) acc[p] = gb1[o];
    const float4* w1 = reinterpret_cast<const float4*>(gW1 + (size_t)o * H3);
    for (int c4 = 0; c4 < H3 / 4; ++c4) {
        const float4 w = w1[c4];
        #pragma unroll
        for (int p = 0; p < 9; ++p) {
            const float4 x = *reinterpret_cast<const float4*>(&comb[p][c4 * 4]);
            acc[p] = fmaf(x.x, w.x, fmaf(x.y, w.y, fmaf(x.z, w.z, fmaf(x.w, w.w, acc[p]))));
        }
    }
    #pragma unroll
    for (int p = 0; p < 9; ++p) y1[p][o] = fmaxf(acc[p], 0.f);
    __syncthreads();
    #pragma unroll
    for (int p = 0; p < 9; ++p) acc[p] = gb2[o];
    const float4* w2 = reinterpret_cast<const float4*>(gW2 + (size_t)o * H3);
    for (int c4 = 0; c4 < H3 / 4; ++c4) {
        const float4 w = w2[c4];
        #pragma unroll
        for (int p = 0; p < 9; ++p) {
            const float4 x = *reinterpret_cast<const float4*>(&y1[p][c4 * 4]);
            acc[p] = fmaf(x.x, w.x, fmaf(x.y, w.y, fmaf(x.z, w.z, fmaf(x.w, w.w, acc[p]))));
        }
    }
    float s = 0.f;
    #pragma unroll
    for (int p = 0; p < 9; ++p) s += fmaxf(acc[p], 0.f);
    (ws + OFF_REAS)[n * H3 + o] = s;
}

// ---------------- K8: out = reasoning @ V_w.T ----------------
__global__ __launch_bounds__(256) void k_out(const float* __restrict__ V_w, const float* __restrict__ ws,
                                             float* __restrict__ out)
{
    __shared__ float rs[NB * H3];
    const int v = blockIdx.x * 256 + threadIdx.x;
    for (int idx = threadIdx.x; idx < NB * H3; idx += 256) rs[idx] = (ws + OFF_REAS)[idx];
    __syncthreads();
    float acc[NB];
    #pragma unroll
    for (int nn = 0; nn < NB; ++nn) acc[nn] = 0.f;
    const float4* vw = reinterpret_cast<const float4*>(V_w + (size_t)v * H3);
    for (int d4 = 0; d4 < H3 / 4; ++d4) {
        const float4 w = vw[d4];
        #pragma unroll
        for (int nn = 0; nn < NB; ++nn) {
            const float4 r = *reinterpret_cast<const float4*>(&rs[nn * H3 + d4 * 4]);
            acc[nn] = fmaf(r.x, w.x, fmaf(r.y, w.y, fmaf(r.z, w.z, fmaf(r.w, w.w, acc[nn]))));
        }
    }
    #pragma unroll
    for (int nn = 0; nn < NB; ++nn) out[(size_t)nn * VOCABN + v] = acc[nn];
}

extern "C" void kernel_launch(void* const* d_in, const int* in_sizes, int n_in,
                              void* d_out, int out_size, void* d_ws, size_t ws_size,
                              hipStream_t stream)
{
    const int*   stories   = (const int*)d_in[0];
    const int*   questions = (const int*)d_in[1];
    const float* emb   = (const float*)d_in[2];
    const float* qWih  = (const float*)d_in[3];
    const float* qWhh  = (const float*)d_in[4];
    const float* qbih  = (const float*)d_in[5];
    const float* qbhh  = (const float*)d_in[6];
    const float* iWih  = (const float*)d_in[7];
    const float* iWhh  = (const float*)d_in[8];
    const float* ibih  = (const float*)d_in[9];
    const float* ibhh  = (const float*)d_in[10];
    const float* Wm    = (const float*)d_in[11];
    const float* Wo_w  = (const float*)d_in[12];
    const float* Wo_b  = (const float*)d_in[13];
    const float* ftW1  = (const float*)d_in[14];
    const float* ftb1  = (const float*)d_in[15];
    const float* ftW2  = (const float*)d_in[16];
    const float* ftb2  = (const float*)d_in[17];
    const float* gW1   = (const float*)d_in[18];
    const float* gb1   = (const float*)d_in[19];
    const float* gW2   = (const float*)d_in[20];
    const float* gb2   = (const float*)d_in[21];
    const float* V_w   = (const float*)d_in[22];
    float* ws  = (float*)d_ws;
    float* out = (float*)d_out;

    hipLaunchKernelGGL(k_gi, dim3(NPOS / GIP), dim3(H3), 0, stream, stories, emb, iWih, ws);
    hipLaunchKernelGGL(k_transpose, dim3(128), dim3(256), 0, stream, qWih, qWhh, ws);
    hipLaunchKernelGGL(k_gru3, dim3(TMN + NB), dim3(512), 0, stream,
                       stories, questions, emb, iWhh, ibih, ibhh, qbih, qbhh, ws);
    hipLaunchKernelGGL(k_ft, dim3(NB), dim3(HH), 0, stream, ws + OFF_Q, ws + OFF_OK, ftW1, ftb1, ftW2, ftb2);
    for (int hp = 0; hp < HOPSN; ++hp) {
        hipLaunchKernelGGL(k_attn, dim3(NB * HEADSN), dim3(HH), 0, stream, Wm, ws, hp);
        hipLaunchKernelGGL(k_buf, dim3(NB), dim3(HH), 0, stream, Wo_w, Wo_b, ftW1, ftb1, ftW2, ftb2, ws, hp);
    }
    hipLaunchKernelGGL(k_rm, dim3(NB), dim3(H3), 0, stream, gW1, gb1, gW2, gb2, ws);
    hipLaunchKernelGGL(k_out, dim3(VOCABN / 256), dim3(256), 0, stream, V_w, ws, out);
}

// Round 5
// 1614.504 us; speedup vs baseline: 9.8221x; 4.8583x over previous
//
#include <hip/hip_runtime.h>
#include <cmath>

#define VOCABN 32000
#define EE 128
#define HH 256
#define H3 768
#define HOPSN 3
#define HEADSN 4
#define NB 32
#define TMN 50
#define WLENN 20
#define TQN 20
#define NPOS (NB*TMN*WLENN)     // 32000 story positions
#define NQPOS (NB*TQN)          // 640 question positions

// workspace offsets (floats)
#define OFF_MEM    0
#define OFF_Q      (OFF_MEM + NB*TMN*HH)
#define OFF_OK     (OFF_Q + NB*HH)
#define OFF_WB     (OFF_OK + NB*HH)
#define OFF_REP    (OFF_WB + NB*HOPSN*HH)
#define OFF_REAS   (OFF_REP + NB*HEADSN*HH)
#define OFF_GI     (OFF_REAS + NB*H3)    // __fp16[(NPOS+NQPOS)*H3]

typedef __fp16 h2 __attribute__((ext_vector_type(2)));

__device__ __forceinline__ float sigm(float x) { return 1.f / (1.f + expf(-x)); }

__device__ __forceinline__ unsigned packh2(float x, float y) {
    h2 h = __builtin_amdgcn_cvt_pkrtz(x, y);
    return __builtin_bit_cast(unsigned, h);
}

__device__ __forceinline__ float fdot2u(unsigned a, unsigned b, float c) {
    return __builtin_amdgcn_fdot2(__builtin_bit_cast(h2, a),
                                  __builtin_bit_cast(h2, b), c, false);
}

// ---------------- K1: gi = x @ Wih.T (+folded biases) for all story+question positions ---------
// blocks 0..499: story (64 pos each); blocks 500..509: question (64 pos each)
#define GIB 64
__global__ __launch_bounds__(768) void k_gi(const int* __restrict__ stories,
                                            const int* __restrict__ questions,
                                            const float* __restrict__ emb,
                                            const float* __restrict__ iWih,
                                            const float* __restrict__ qWih,
                                            const float* __restrict__ ibih, const float* __restrict__ ibhh,
                                            const float* __restrict__ qbih, const float* __restrict__ qbhh,
                                            float* __restrict__ ws)
{
    __shared__ unsigned xs[GIB][EE / 2];   // 64 pos x 64 packed-f16 pairs (16 KB)
    __fp16* __restrict__ gi = (__fp16*)(ws + OFF_GI);
    const int j = threadIdx.x;             // gate row 0..767
    const bool isq = blockIdx.x >= (NPOS / GIB);
    const int pblk = isq ? (blockIdx.x - NPOS / GIB) : blockIdx.x;
    const int p0 = pblk * GIB;
    const size_t g0 = (isq ? (size_t)NPOS : 0) + (size_t)p0;
    const int* __restrict__ toks = isq ? (questions + p0) : (stories + p0);
    const float* __restrict__ Wih = isq ? qWih : iWih;
    const float* __restrict__ bih = isq ? qbih : ibih;
    const float* __restrict__ bhh = isq ? qbhh : ibhh;
    // fold biases: r,z rows get bih+bhh; n rows get bih only (bhh_n applied inside r*(...))
    const float bias = (j < 2 * HH) ? (bih[j] + bhh[j]) : bih[j];
    // pack Wih row j into 64 f16-pairs
    unsigned wreg[EE / 2];
    const float2* wrow = reinterpret_cast<const float2*>(Wih + (size_t)j * EE);
    #pragma unroll
    for (int c = 0; c < EE / 2; ++c) {
        const float2 w2 = wrow[c];
        wreg[c] = packh2(w2.x, w2.y);
    }
    for (int idx = j; idx < GIB * (EE / 2); idx += H3) {
        const int p = idx >> 6, c = idx & 63;
        const int tok = toks[p];
        const float2 e2 = reinterpret_cast<const float2*>(emb + (size_t)tok * EE)[c];
        xs[p][c] = packh2(e2.x, e2.y);
    }
    __syncthreads();
    for (int p = 0; p < GIB; ++p) {
        float acc = bias;
        #pragma unroll
        for (int c = 0; c < EE / 2; ++c) acc = fdot2u(xs[p][c], wreg[c], acc);
        gi[(g0 + p) * H3 + j] = (__fp16)acc;
    }
}

// ---------------- K2: recurrent GRUs, weights register-resident as packed f16 ------------------
// blocks 0..49: slot chains (640 steps); blocks 50..81: question chains (20 steps)
__global__ __launch_bounds__(1024, 4) void k_gru4(
    const float* __restrict__ iWhh, const float* __restrict__ qWhh,
    const float* __restrict__ ibhh, const float* __restrict__ qbhh,
    float* __restrict__ ws)
{
    __shared__ unsigned hp32[HH / 2];      // h as 128 packed f16 pairs
    __shared__ float red[HH * 13];         // stride-13: conflict-free partial exchange
    const int tid = threadIdx.x;
    const int j = tid & 255, kq = tid >> 8;
    const int blk = blockIdx.x;
    const bool isq = blk >= TMN;
    const float* __restrict__ Whh = isq ? qWhh : iWhh;
    // weights: gate rows {j, 256+j, 512+j}, k range [kq*64, kq*64+64) -> 3 x 32 packed pairs
    unsigned wg0[32], wg1[32], wg2[32];
    {
        const float2* r0 = reinterpret_cast<const float2*>(Whh + (size_t)j * HH + kq * 64);
        const float2* r1 = reinterpret_cast<const float2*>(Whh + (size_t)(HH + j) * HH + kq * 64);
        const float2* r2 = reinterpret_cast<const float2*>(Whh + (size_t)(2 * HH + j) * HH + kq * 64);
        #pragma unroll
        for (int c = 0; c < 32; ++c) { const float2 a = r0[c]; wg0[c] = packh2(a.x, a.y); }
        #pragma unroll
        for (int c = 0; c < 32; ++c) { const float2 a = r1[c]; wg1[c] = packh2(a.x, a.y); }
        #pragma unroll
        for (int c = 0; c < 32; ++c) { const float2 a = r2[c]; wg2[c] = packh2(a.x, a.y); }
    }
    float bnH = 0.f, hstate = 0.f;
    if (kq == 0) bnH = (isq ? qbhh : ibhh)[2 * HH + j];
    if (tid < HH / 2) hp32[tid] = 0u;
    const __fp16* __restrict__ gib = (const __fp16*)(ws + OFF_GI)
                                     + (isq ? (size_t)NPOS * H3 : 0);
    float* __restrict__ memv = ws + OFF_MEM;
    float* __restrict__ qv   = ws + OFF_Q;
    __syncthreads();

    const int nOuter = isq ? 1 : NB;
    const int c = isq ? (blk - TMN) : blk;
    for (int n = 0; n < nOuter; ++n) {
        for (int t = 0; t < WLENN; ++t) {
            const int pos = isq ? (c * TQN + t) : ((n * TMN + c) * WLENN + t);
            float gir = 0.f, giz = 0.f, gin = 0.f;
            if (kq == 0) {
                const size_t gb = (size_t)pos * H3;
                gir = (float)gib[gb + j];
                giz = (float)gib[gb + HH + j];
                gin = (float)gib[gb + 2 * HH + j];
            }
            float a0 = 0.f, a1 = 0.f, a2 = 0.f;
            const uint4* hp4 = reinterpret_cast<const uint4*>(hp32);
            #pragma unroll
            for (int c4 = 0; c4 < 8; ++c4) {
                const uint4 hh = hp4[kq * 8 + c4];   // wave-uniform address: LDS broadcast
                a0 = fdot2u(hh.x, wg0[4 * c4 + 0], a0);
                a0 = fdot2u(hh.y, wg0[4 * c4 + 1], a0);
                a0 = fdot2u(hh.z, wg0[4 * c4 + 2], a0);
                a0 = fdot2u(hh.w, wg0[4 * c4 + 3], a0);
                a1 = fdot2u(hh.x, wg1[4 * c4 + 0], a1);
                a1 = fdot2u(hh.y, wg1[4 * c4 + 1], a1);
                a1 = fdot2u(hh.z, wg1[4 * c4 + 2], a1);
                a1 = fdot2u(hh.w, wg1[4 * c4 + 3], a1);
                a2 = fdot2u(hh.x, wg2[4 * c4 + 0], a2);
                a2 = fdot2u(hh.y, wg2[4 * c4 + 1], a2);
                a2 = fdot2u(hh.z, wg2[4 * c4 + 2], a2);
                a2 = fdot2u(hh.w, wg2[4 * c4 + 3], a2);
            }
            red[j * 13 + kq]     = a0;
            red[j * 13 + 4 + kq] = a1;
            red[j * 13 + 8 + kq] = a2;
            __syncthreads();
            if (kq == 0) {
                const float* rr = red + j * 13;
                const float s0 = (rr[0] + rr[1]) + (rr[2] + rr[3]);
                const float s1 = (rr[4] + rr[5]) + (rr[6] + rr[7]);
                const float s2 = (rr[8] + rr[9]) + (rr[10] + rr[11]);
                const float r  = sigm(s0 + gir);
                const float z  = sigm(s1 + giz);
                const float nn = tanhf(gin + r * (s2 + bnH));
                hstate = (1.f - z) * nn + z * hstate;
                reinterpret_cast<__fp16*>(hp32)[j] = (__fp16)hstate;
                if (t == WLENN - 1) {
                    if (isq) qv[c * HH + j] = hstate;
                    else     memv[(size_t)(n * TMN + c) * HH + j] = hstate;
                }
            }
            __syncthreads();
        }
    }
}

// ---------------- K3: ft(x), one block per row ----------------
__global__ __launch_bounds__(256) void k_ft(const float* __restrict__ src, float* __restrict__ dst,
                                            const float* __restrict__ W1, const float* __restrict__ b1,
                                            const float* __restrict__ W2, const float* __restrict__ b2)
{
    __shared__ float xr[HH];
    __shared__ float y1[HH];
    const int n = blockIdx.x, j = threadIdx.x;
    xr[j] = src[n * HH + j];
    __syncthreads();
    float acc = b1[j];
    const float4* w1 = reinterpret_cast<const float4*>(W1 + j * HH);
    #pragma unroll 4
    for (int k4 = 0; k4 < HH / 4; ++k4) {
        const float4 w = w1[k4];
        const float4 x = *reinterpret_cast<const float4*>(&xr[k4 * 4]);
        acc = fmaf(x.x, w.x, fmaf(x.y, w.y, fmaf(x.z, w.z, fmaf(x.w, w.w, acc))));
    }
    y1[j] = fmaxf(acc, 0.f);
    __syncthreads();
    acc = b2[j];
    const float4* w2 = reinterpret_cast<const float4*>(W2 + j * HH);
    #pragma unroll 4
    for (int k4 = 0; k4 < HH / 4; ++k4) {
        const float4 w = w2[k4];
        const float4 x = *reinterpret_cast<const float4*>(&y1[k4 * 4]);
        acc = fmaf(x.x, w.x, fmaf(x.y, w.y, fmaf(x.z, w.z, fmaf(x.w, w.w, acc))));
    }
    dst[n * HH + j] = fmaxf(acc, 0.f);
}

// ---------------- K4: attention scores + rep for one hop; block = (n, head) ----------------
__global__ __launch_bounds__(256) void k_attn(const float* __restrict__ Wm, float* __restrict__ ws, int hp)
{
    __shared__ float mem_s[TMN][HH];
    __shared__ float ok_s[HH];
    __shared__ float wred[4][TMN];
    __shared__ float sc[TMN];
    const int n = blockIdx.x / HEADSN, hh = blockIdx.x % HEADSN;
    const int e = threadIdx.x;
    const float* __restrict__ memory = ws + OFF_MEM + n * TMN * HH;
    for (int idx = e; idx < TMN * HH; idx += HH)
        (&mem_s[0][0])[idx] = memory[idx];
    ok_s[e] = (ws + OFF_OK)[n * HH + e];
    __syncthreads();

    float p[TMN];
    #pragma unroll
    for (int t = 0; t < TMN; ++t) p[t] = 0.f;
    const float4* wrow = reinterpret_cast<const float4*>(Wm + ((size_t)(hp * HEADSN + hh) * HH + e) * HH);
    for (int d4 = 0; d4 < HH / 4; ++d4) {
        const float4 w = wrow[d4];
        #pragma unroll
        for (int t = 0; t < TMN; ++t) {
            const float4 m = *reinterpret_cast<const float4*>(&mem_s[t][d4 * 4]);
            p[t] = fmaf(m.x, w.x, fmaf(m.y, w.y, fmaf(m.z, w.z, fmaf(m.w, w.w, p[t]))));
        }
    }
    const float okv = ok_s[e];
    const int lane = e & 63, wv = e >> 6;
    #pragma unroll
    for (int t = 0; t < TMN; ++t) {
        float v = tanhf(p[t]) * okv;
        #pragma unroll
        for (int off = 32; off > 0; off >>= 1) v += __shfl_xor(v, off);
        if (lane == 0) wred[wv][t] = v;
    }
    __syncthreads();
    if (e < TMN) sc[e] = wred[0][e] + wred[1][e] + wred[2][e] + wred[3][e];
    __syncthreads();
    if (e == 0) {
        float mx = sc[0];
        for (int t = 1; t < TMN; ++t) mx = fmaxf(mx, sc[t]);
        float sum = 0.f;
        for (int t = 0; t < TMN; ++t) { const float ex = expf(sc[t] - mx); sc[t] = ex; sum += ex; }
        const float inv = 1.f / sum;
        for (int t = 0; t < TMN; ++t) sc[t] *= inv;
    }
    __syncthreads();
    float r = 0.f;
    #pragma unroll
    for (int t = 0; t < TMN; ++t) r = fmaf(sc[t], mem_s[t][e], r);
    (ws + OFF_REP)[(n * HEADSN + hh) * HH + e] = r;
}

// ---------------- K5: buf = rep @ Wo_w.T + Wo_b; o_k = ft(buf) ----------------
__global__ __launch_bounds__(256) void k_buf(const float* __restrict__ Wo_w, const float* __restrict__ Wo_b,
                                             const float* __restrict__ W1, const float* __restrict__ b1,
                                             const float* __restrict__ W2, const float* __restrict__ b2,
                                             float* __restrict__ ws, int hp)
{
    __shared__ float repf[HEADSN * HH];
    __shared__ float bufs[HH];
    __shared__ float y1[HH];
    const int n = blockIdx.x, j = threadIdx.x;
    const float* __restrict__ rep = ws + OFF_REP + n * HEADSN * HH;
    for (int idx = j; idx < HEADSN * HH; idx += HH) repf[idx] = rep[idx];
    __syncthreads();
    float acc = Wo_b[hp * HH + j];
    const float4* wrow = reinterpret_cast<const float4*>(Wo_w + ((size_t)hp * HH + j) * (HEADSN * HH));
    #pragma unroll 4
    for (int c4 = 0; c4 < HEADSN * HH / 4; ++c4) {
        const float4 w = wrow[c4];
        const float4 x = *reinterpret_cast<const float4*>(&repf[c4 * 4]);
        acc = fmaf(x.x, w.x, fmaf(x.y, w.y, fmaf(x.z, w.z, fmaf(x.w, w.w, acc))));
    }
    (ws + OFF_WB)[(n * HOPSN + hp) * HH + j] = acc;
    bufs[j] = acc;
    __syncthreads();
    float a1 = b1[j];
    const float4* w1 = reinterpret_cast<const float4*>(W1 + j * HH);
    #pragma unroll 4
    for (int k4 = 0; k4 < HH / 4; ++k4) {
        const float4 w = w1[k4];
        const float4 x = *reinterpret_cast<const float4*>(&bufs[k4 * 4]);
        a1 = fmaf(x.x, w.x, fmaf(x.y, w.y, fmaf(x.z, w.z, fmaf(x.w, w.w, a1))));
    }
    y1[j] = fmaxf(a1, 0.f);
    __syncthreads();
    float a2 = b2[j];
    const float4* w2 = reinterpret_cast<const float4*>(W2 + j * HH);
    #pragma unroll 4
    for (int k4 = 0; k4 < HH / 4; ++k4) {
        const float4 w = w2[k4];
        const float4 x = *reinterpret_cast<const float4*>(&y1[k4 * 4]);
        a2 = fmaf(x.x, w.x, fmaf(x.y, w.y, fmaf(x.z, w.z, fmaf(x.w, w.w, a2))));
    }
    (ws + OFF_OK)[n * HH + j] = fmaxf(a2, 0.f);
}

// ---------------- K6: relation MLP, one block per n; sums 9 pairs into REAS ----------------
__global__ __launch_bounds__(768) void k_rm(const float* __restrict__ gW1, const float* __restrict__ gb1,
                                            const float* __restrict__ gW2, const float* __restrict__ gb2,
                                            float* __restrict__ ws)
{
    __shared__ float comb[9][H3];
    __shared__ float y1[9][H3];
    const int n = blockIdx.x;
    const int o = threadIdx.x;
    const float* __restrict__ wb = ws + OFF_WB + n * HOPSN * HH;
    const float* __restrict__ qv = ws + OFF_Q + n * HH;
    #pragma unroll
    for (int p = 0; p < 9; ++p) {
        const int ii = p / 3, jj = p % 3;
        float v;
        if (o < HH)            v = wb[jj * HH + o];
        else if (o < 2 * HH)   v = wb[ii * HH + (o - HH)];
        else                   v = qv[o - 2 * HH];
        comb[p][o] = v;
    }
    __syncthreads();
    float acc[9];
    #pragma unroll
    for (int p = 0; p < 9; ++p) acc[p] = gb1[o];
    const float4* w1 = reinterpret_cast<const float4*>(gW1 + (size_t)o * H3);
    for (int c4 = 0; c4 < H3 / 4; ++c4) {
        const float4 w = w1[c4];
        #pragma unroll
        for (int p = 0; p < 9; ++p) {
            const float4 x = *reinterpret_cast<const float4*>(&comb[p][c4 * 4]);
            acc[p] = fmaf(x.x, w.x, fmaf(x.y, w.y, fmaf(x.z, w.z, fmaf(x.w, w.w, acc[p]))));
        }
    }
    #pragma unroll
    for (int p = 0; p < 9; ++p) y1[p][o] = fmaxf(acc[p], 0.f);
    __syncthreads();
    #pragma unroll
    for (int p = 0; p < 9; ++p) acc[p] = gb2[o];
    const float4* w2 = reinterpret_cast<const float4*>(gW2 + (size_t)o * H3);
    for (int c4 = 0; c4 < H3 / 4; ++c4) {
        const float4 w = w2[c4];
        #pragma unroll
        for (int p = 0; p < 9; ++p) {
            const float4 x = *reinterpret_cast<const float4*>(&y1[p][c4 * 4]);
            acc[p] = fmaf(x.x, w.x, fmaf(x.y, w.y, fmaf(x.z, w.z, fmaf(x.w, w.w, acc[p]))));
        }
    }
    float s = 0.f;
    #pragma unroll
    for (int p = 0; p < 9; ++p) s += fmaxf(acc[p], 0.f);
    (ws + OFF_REAS)[n * H3 + o] = s;
}

// ---------------- K7: out = reasoning @ V_w.T ----------------
__global__ __launch_bounds__(256) void k_out(const float* __restrict__ V_w, const float* __restrict__ ws,
                                             float* __restrict__ out)
{
    __shared__ float rs[NB * H3];
    const int v = blockIdx.x * 256 + threadIdx.x;
    for (int idx = threadIdx.x; idx < NB * H3; idx += 256) rs[idx] = (ws + OFF_REAS)[idx];
    __syncthreads();
    float acc[NB];
    #pragma unroll
    for (int nn = 0; nn < NB; ++nn) acc[nn] = 0.f;
    const float4* vw = reinterpret_cast<const float4*>(V_w + (size_t)v * H3);
    for (int d4 = 0; d4 < H3 / 4; ++d4) {
        const float4 w = vw[d4];
        #pragma unroll
        for (int nn = 0; nn < NB; ++nn) {
            const float4 r = *reinterpret_cast<const float4*>(&rs[nn * H3 + d4 * 4]);
            acc[nn] = fmaf(r.x, w.x, fmaf(r.y, w.y, fmaf(r.z, w.z, fmaf(r.w, w.w, acc[nn]))));
        }
    }
    #pragma unroll
    for (int nn = 0; nn < NB; ++nn) out[(size_t)nn * VOCABN + v] = acc[nn];
}

extern "C" void kernel_launch(void* const* d_in, const int* in_sizes, int n_in,
                              void* d_out, int out_size, void* d_ws, size_t ws_size,
                              hipStream_t stream)
{
    const int*   stories   = (const int*)d_in[0];
    const int*   questions = (const int*)d_in[1];
    const float* emb   = (const float*)d_in[2];
    const float* qWih  = (const float*)d_in[3];
    const float* qWhh  = (const float*)d_in[4];
    const float* qbih  = (const float*)d_in[5];
    const float* qbhh  = (const float*)d_in[6];
    const float* iWih  = (const float*)d_in[7];
    const float* iWhh  = (const float*)d_in[8];
    const float* ibih  = (const float*)d_in[9];
    const float* ibhh  = (const float*)d_in[10];
    const float* Wm    = (const float*)d_in[11];
    const float* Wo_w  = (const float*)d_in[12];
    const float* Wo_b  = (const float*)d_in[13];
    const float* ftW1  = (const float*)d_in[14];
    const float* ftb1  = (const float*)d_in[15];
    const float* ftW2  = (const float*)d_in[16];
    const float* ftb2  = (const float*)d_in[17];
    const float* gW1   = (const float*)d_in[18];
    const float* gb1   = (const float*)d_in[19];
    const float* gW2   = (const float*)d_in[20];
    const float* gb2   = (const float*)d_in[21];
    const float* V_w   = (const float*)d_in[22];
    float* ws  = (float*)d_ws;
    float* out = (float*)d_out;

    hipLaunchKernelGGL(k_gi, dim3((NPOS + NQPOS) / GIB), dim3(H3), 0, stream,
                       stories, questions, emb, iWih, qWih, ibih, ibhh, qbih, qbhh, ws);
    hipLaunchKernelGGL(k_gru4, dim3(TMN + NB), dim3(1024), 0, stream,
                       iWhh, qWhh, ibhh, qbhh, ws);
    hipLaunchKernelGGL(k_ft, dim3(NB), dim3(HH), 0, stream, ws + OFF_Q, ws + OFF_OK, ftW1, ftb1, ftW2, ftb2);
    for (int hp = 0; hp < HOPSN; ++hp) {
        hipLaunchKernelGGL(k_attn, dim3(NB * HEADSN), dim3(HH), 0, stream, Wm, ws, hp);
        hipLaunchKernelGGL(k_buf, dim3(NB), dim3(HH), 0, stream, Wo_w, Wo_b, ftW1, ftb1, ftW2, ftb2, ws, hp);
    }
    hipLaunchKernelGGL(k_rm, dim3(NB), dim3(H3), 0, stream, gW1, gb1, gW2, gb2, ws);
    hipLaunchKernelGGL(k_out, dim3(VOCABN / 256), dim3(256), 0, stream, V_w, ws, out);
}

// Round 6
// 1481.150 us; speedup vs baseline: 10.7064x; 1.0900x over previous
//
#include <hip/hip_runtime.h>
#include <cmath>

#define VOCABN 32000
#define EE 128
#define HH 256
#define H3 768
#define HOPSN 3
#define HEADSN 4
#define NB 32
#define TMN 50
#define WLENN 20
#define TQN 20
#define NPOS (NB*TMN*WLENN)     // 32000 story positions
#define NQPOS (NB*TQN)          // 640 question positions

// workspace offsets (floats)
#define OFF_MEM    0
#define OFF_Q      (OFF_MEM + NB*TMN*HH)
#define OFF_OK     (OFF_Q + NB*HH)
#define OFF_WB     (OFF_OK + NB*HH)
#define OFF_REP    (OFF_WB + NB*HOPSN*HH)
#define OFF_REAS   (OFF_REP + NB*HEADSN*HH)
#define OFF_Y1     (OFF_REAS + NB*H3)                 // [32][9][768]
#define OFF_GI     (OFF_Y1 + NB*9*H3)                 // __fp16[(NPOS+NQPOS)*H3]

typedef __fp16 h2 __attribute__((ext_vector_type(2)));

__device__ __forceinline__ float sigm(float x) { return 1.f / (1.f + expf(-x)); }

__device__ __forceinline__ unsigned packh2(float x, float y) {
    h2 h = __builtin_amdgcn_cvt_pkrtz(x, y);
    return __builtin_bit_cast(unsigned, h);
}

__device__ __forceinline__ float fdot2u(unsigned a, unsigned b, float c) {
    return __builtin_amdgcn_fdot2(__builtin_bit_cast(h2, a),
                                  __builtin_bit_cast(h2, b), c, false);
}

// ---------------- K1: gi = x @ Wih.T (+folded biases) for all story+question positions ---------
#define GIB 64
__global__ __launch_bounds__(768) void k_gi(const int* __restrict__ stories,
                                            const int* __restrict__ questions,
                                            const float* __restrict__ emb,
                                            const float* __restrict__ iWih,
                                            const float* __restrict__ qWih,
                                            const float* __restrict__ ibih, const float* __restrict__ ibhh,
                                            const float* __restrict__ qbih, const float* __restrict__ qbhh,
                                            float* __restrict__ ws)
{
    __shared__ unsigned xs[GIB][EE / 2];   // 64 pos x 64 packed-f16 pairs (16 KB)
    __fp16* __restrict__ gi = (__fp16*)(ws + OFF_GI);
    const int j = threadIdx.x;             // gate row 0..767
    const bool isq = blockIdx.x >= (NPOS / GIB);
    const int pblk = isq ? (blockIdx.x - NPOS / GIB) : blockIdx.x;
    const int p0 = pblk * GIB;
    const size_t g0 = (isq ? (size_t)NPOS : 0) + (size_t)p0;
    const int* __restrict__ toks = isq ? (questions + p0) : (stories + p0);
    const float* __restrict__ Wih = isq ? qWih : iWih;
    const float* __restrict__ bih = isq ? qbih : ibih;
    const float* __restrict__ bhh = isq ? qbhh : ibhh;
    const float bias = (j < 2 * HH) ? (bih[j] + bhh[j]) : bih[j];
    unsigned wreg[EE / 2];
    const float2* wrow = reinterpret_cast<const float2*>(Wih + (size_t)j * EE);
    #pragma unroll
    for (int c = 0; c < EE / 2; ++c) {
        const float2 w2 = wrow[c];
        wreg[c] = packh2(w2.x, w2.y);
    }
    for (int idx = j; idx < GIB * (EE / 2); idx += H3) {
        const int p = idx >> 6, c = idx & 63;
        const int tok = toks[p];
        const float2 e2 = reinterpret_cast<const float2*>(emb + (size_t)tok * EE)[c];
        xs[p][c] = packh2(e2.x, e2.y);
    }
    __syncthreads();
    for (int p = 0; p < GIB; ++p) {
        const uint4* x4 = reinterpret_cast<const uint4*>(&xs[p][0]);
        float acc = bias;
        #pragma unroll
        for (int c4 = 0; c4 < 16; ++c4) {
            const uint4 xv = x4[c4];               // one ds_read_b128, wave-broadcast
            acc = fdot2u(xv.x, wreg[4 * c4 + 0], acc);
            acc = fdot2u(xv.y, wreg[4 * c4 + 1], acc);
            acc = fdot2u(xv.z, wreg[4 * c4 + 2], acc);
            acc = fdot2u(xv.w, wreg[4 * c4 + 3], acc);
        }
        gi[(g0 + p) * H3 + j] = (__fp16)acc;
    }
}

// ---------------- K2: recurrent GRUs, 512 thr, 192 weight regs/thread (256-VGPR cap) ----------
// blocks 0..49: slot chains (640 steps); blocks 50..81: question chains (20 steps)
__global__ __launch_bounds__(512, 2) void k_gru5(
    const float* __restrict__ iWhh, const float* __restrict__ qWhh,
    const float* __restrict__ ibhh, const float* __restrict__ qbhh,
    float* __restrict__ ws)
{
    __shared__ unsigned hp32[HH / 2];      // h as 128 packed f16 pairs
    __shared__ float red[HH * 5];          // stride-5 partial exchange (2-way bank max)
    const int tid = threadIdx.x;
    const int j = tid & 255, kh = tid >> 8;      // output index, k-half (0/1)
    const int blk = blockIdx.x;
    const bool isq = blk >= TMN;
    const float* __restrict__ Whh = isq ? qWhh : iWhh;
    // thread (j,kh) holds gate rows {j, 256+j, 512+j}, k in [kh*128, kh*128+128) -> 3x64 uints
    unsigned wg0[64], wg1[64], wg2[64];
    {
        const float2* r0 = reinterpret_cast<const float2*>(Whh + (size_t)j * HH + kh * 128);
        const float2* r1 = reinterpret_cast<const float2*>(Whh + (size_t)(HH + j) * HH + kh * 128);
        const float2* r2 = reinterpret_cast<const float2*>(Whh + (size_t)(2 * HH + j) * HH + kh * 128);
        #pragma unroll
        for (int c = 0; c < 64; ++c) { const float2 a = r0[c]; wg0[c] = packh2(a.x, a.y); }
        #pragma unroll
        for (int c = 0; c < 64; ++c) { const float2 a = r1[c]; wg1[c] = packh2(a.x, a.y); }
        #pragma unroll
        for (int c = 0; c < 64; ++c) { const float2 a = r2[c]; wg2[c] = packh2(a.x, a.y); }
    }
    float bnH = 0.f, hstate = 0.f;
    if (kh == 0) bnH = (isq ? qbhh : ibhh)[2 * HH + j];
    if (tid < HH / 2) hp32[tid] = 0u;
    const __fp16* __restrict__ gib = (const __fp16*)(ws + OFF_GI)
                                     + (isq ? (size_t)NPOS * H3 : 0);
    float* __restrict__ memv = ws + OFF_MEM;
    float* __restrict__ qv   = ws + OFF_Q;
    __syncthreads();

    const int nOuter = isq ? 1 : NB;
    const int c = isq ? (blk - TMN) : blk;
    for (int n = 0; n < nOuter; ++n) {
        for (int t = 0; t < WLENN; ++t) {
            const int pos = isq ? (c * TQN + t) : ((n * TMN + c) * WLENN + t);
            float gir = 0.f, giz = 0.f, gin = 0.f;
            if (kh == 0) {     // issue early, consumed after the FMA loop
                const size_t gb = (size_t)pos * H3;
                gir = (float)gib[gb + j];
                giz = (float)gib[gb + HH + j];
                gin = (float)gib[gb + 2 * HH + j];
            }
            float a0 = 0.f, a1 = 0.f, a2 = 0.f;
            const uint4* hp4 = reinterpret_cast<const uint4*>(hp32);
            #pragma unroll
            for (int c4 = 0; c4 < 16; ++c4) {
                const uint4 hh = hp4[kh * 16 + c4];   // wave-uniform: LDS broadcast
                a0 = fdot2u(hh.x, wg0[4 * c4 + 0], a0);
                a0 = fdot2u(hh.y, wg0[4 * c4 + 1], a0);
                a0 = fdot2u(hh.z, wg0[4 * c4 + 2], a0);
                a0 = fdot2u(hh.w, wg0[4 * c4 + 3], a0);
                a1 = fdot2u(hh.x, wg1[4 * c4 + 0], a1);
                a1 = fdot2u(hh.y, wg1[4 * c4 + 1], a1);
                a1 = fdot2u(hh.z, wg1[4 * c4 + 2], a1);
                a1 = fdot2u(hh.w, wg1[4 * c4 + 3], a1);
                a2 = fdot2u(hh.x, wg2[4 * c4 + 0], a2);
                a2 = fdot2u(hh.y, wg2[4 * c4 + 1], a2);
                a2 = fdot2u(hh.z, wg2[4 * c4 + 2], a2);
                a2 = fdot2u(hh.w, wg2[4 * c4 + 3], a2);
            }
            if (kh == 1) { red[j * 5 + 0] = a0; red[j * 5 + 1] = a1; red[j * 5 + 2] = a2; }
            __syncthreads();
            if (kh == 0) {
                const float* rr = red + j * 5;
                const float r  = sigm(a0 + rr[0] + gir);
                const float z  = sigm(a1 + rr[1] + giz);
                const float nn = tanhf(gin + r * (a2 + rr[2] + bnH));
                hstate = (1.f - z) * nn + z * hstate;
                reinterpret_cast<__fp16*>(hp32)[j] = (__fp16)hstate;
                if (t == WLENN - 1) {
                    if (isq) qv[c * HH + j] = hstate;
                    else     memv[(size_t)(n * TMN + c) * HH + j] = hstate;
                }
            }
            __syncthreads();
        }
    }
}

// ---------------- K3: ft(x), one block per row ----------------
__global__ __launch_bounds__(256) void k_ft(const float* __restrict__ src, float* __restrict__ dst,
                                            const float* __restrict__ W1, const float* __restrict__ b1,
                                            const float* __restrict__ W2, const float* __restrict__ b2)
{
    __shared__ float xr[HH];
    __shared__ float y1[HH];
    const int n = blockIdx.x, j = threadIdx.x;
    xr[j] = src[n * HH + j];
    __syncthreads();
    float acc = b1[j];
    const float4* w1 = reinterpret_cast<const float4*>(W1 + j * HH);
    #pragma unroll 4
    for (int k4 = 0; k4 < HH / 4; ++k4) {
        const float4 w = w1[k4];
        const float4 x = *reinterpret_cast<const float4*>(&xr[k4 * 4]);
        acc = fmaf(x.x, w.x, fmaf(x.y, w.y, fmaf(x.z, w.z, fmaf(x.w, w.w, acc))));
    }
    y1[j] = fmaxf(acc, 0.f);
    __syncthreads();
    acc = b2[j];
    const float4* w2 = reinterpret_cast<const float4*>(W2 + j * HH);
    #pragma unroll 4
    for (int k4 = 0; k4 < HH / 4; ++k4) {
        const float4 w = w2[k4];
        const float4 x = *reinterpret_cast<const float4*>(&y1[k4 * 4]);
        acc = fmaf(x.x, w.x, fmaf(x.y, w.y, fmaf(x.z, w.z, fmaf(x.w, w.w, acc))));
    }
    dst[n * HH + j] = fmaxf(acc, 0.f);
}

// ---------------- K4: attention scores + rep for one hop; block = (n, head) ----------------
__global__ __launch_bounds__(256) void k_attn(const float* __restrict__ Wm, float* __restrict__ ws, int hp)
{
    __shared__ float mem_s[TMN][HH];
    __shared__ float ok_s[HH];
    __shared__ float wred[4][TMN];
    __shared__ float sc[TMN];
    const int n = blockIdx.x / HEADSN, hh = blockIdx.x % HEADSN;
    const int e = threadIdx.x;
    const float* __restrict__ memory = ws + OFF_MEM + n * TMN * HH;
    for (int idx = e; idx < TMN * HH; idx += HH)
        (&mem_s[0][0])[idx] = memory[idx];
    ok_s[e] = (ws + OFF_OK)[n * HH + e];
    __syncthreads();

    float p[TMN];
    #pragma unroll
    for (int t = 0; t < TMN; ++t) p[t] = 0.f;
    const float4* wrow = reinterpret_cast<const float4*>(Wm + ((size_t)(hp * HEADSN + hh) * HH + e) * HH);
    for (int d4 = 0; d4 < HH / 4; ++d4) {
        const float4 w = wrow[d4];
        #pragma unroll
        for (int t = 0; t < TMN; ++t) {
            const float4 m = *reinterpret_cast<const float4*>(&mem_s[t][d4 * 4]);
            p[t] = fmaf(m.x, w.x, fmaf(m.y, w.y, fmaf(m.z, w.z, fmaf(m.w, w.w, p[t]))));
        }
    }
    const float okv = ok_s[e];
    const int lane = e & 63, wv = e >> 6;
    #pragma unroll
    for (int t = 0; t < TMN; ++t) {
        float v = tanhf(p[t]) * okv;
        #pragma unroll
        for (int off = 32; off > 0; off >>= 1) v += __shfl_xor(v, off);
        if (lane == 0) wred[wv][t] = v;
    }
    __syncthreads();
    if (e < TMN) sc[e] = wred[0][e] + wred[1][e] + wred[2][e] + wred[3][e];
    __syncthreads();
    if (e == 0) {
        float mx = sc[0];
        for (int t = 1; t < TMN; ++t) mx = fmaxf(mx, sc[t]);
        float sum = 0.f;
        for (int t = 0; t < TMN; ++t) { const float ex = expf(sc[t] - mx); sc[t] = ex; sum += ex; }
        const float inv = 1.f / sum;
        for (int t = 0; t < TMN; ++t) sc[t] *= inv;
    }
    __syncthreads();
    float r = 0.f;
    #pragma unroll
    for (int t = 0; t < TMN; ++t) r = fmaf(sc[t], mem_s[t][e], r);
    (ws + OFF_REP)[(n * HEADSN + hh) * HH + e] = r;
}

// ---------------- K5: buf = rep @ Wo_w.T + Wo_b; o_k = ft(buf) ----------------
__global__ __launch_bounds__(256) void k_buf(const float* __restrict__ Wo_w, const float* __restrict__ Wo_b,
                                             const float* __restrict__ W1, const float* __restrict__ b1,
                                             const float* __restrict__ W2, const float* __restrict__ b2,
                                             float* __restrict__ ws, int hp)
{
    __shared__ float repf[HEADSN * HH];
    __shared__ float bufs[HH];
    __shared__ float y1[HH];
    const int n = blockIdx.x, j = threadIdx.x;
    const float* __restrict__ rep = ws + OFF_REP + n * HEADSN * HH;
    for (int idx = j; idx < HEADSN * HH; idx += HH) repf[idx] = rep[idx];
    __syncthreads();
    float acc = Wo_b[hp * HH + j];
    const float4* wrow = reinterpret_cast<const float4*>(Wo_w + ((size_t)hp * HH + j) * (HEADSN * HH));
    #pragma unroll 4
    for (int c4 = 0; c4 < HEADSN * HH / 4; ++c4) {
        const float4 w = wrow[c4];
        const float4 x = *reinterpret_cast<const float4*>(&repf[c4 * 4]);
        acc = fmaf(x.x, w.x, fmaf(x.y, w.y, fmaf(x.z, w.z, fmaf(x.w, w.w, acc))));
    }
    (ws + OFF_WB)[(n * HOPSN + hp) * HH + j] = acc;
    bufs[j] = acc;
    __syncthreads();
    float a1 = b1[j];
    const float4* w1 = reinterpret_cast<const float4*>(W1 + j * HH);
    #pragma unroll 4
    for (int k4 = 0; k4 < HH / 4; ++k4) {
        const float4 w = w1[k4];
        const float4 x = *reinterpret_cast<const float4*>(&bufs[k4 * 4]);
        a1 = fmaf(x.x, w.x, fmaf(x.y, w.y, fmaf(x.z, w.z, fmaf(x.w, w.w, a1))));
    }
    y1[j] = fmaxf(a1, 0.f);
    __syncthreads();
    float a2 = b2[j];
    const float4* w2 = reinterpret_cast<const float4*>(W2 + j * HH);
    #pragma unroll 4
    for (int k4 = 0; k4 < HH / 4; ++k4) {
        const float4 w = w2[k4];
        const float4 x = *reinterpret_cast<const float4*>(&y1[k4 * 4]);
        a2 = fmaf(x.x, w.x, fmaf(x.y, w.y, fmaf(x.z, w.z, fmaf(x.w, w.w, a2))));
    }
    (ws + OFF_OK)[n * HH + j] = fmaxf(a2, 0.f);
}

// ---------------- K6a: RM layer 1 — y1[n][9][o] ; grid = 32n x 3 o-tiles ----------------
__global__ __launch_bounds__(256) void k_rm1(const float* __restrict__ gW1, const float* __restrict__ gb1,
                                             float* __restrict__ ws)
{
    __shared__ float comb[9 * H3];   // 27.6 KB
    const int n = blockIdx.x / 3, ot = blockIdx.x % 3;
    const int o = ot * 256 + threadIdx.x;
    const float* __restrict__ wb = ws + OFF_WB + n * HOPSN * HH;
    const float* __restrict__ qv = ws + OFF_Q + n * HH;
    for (int idx = threadIdx.x; idx < 9 * H3; idx += 256) {
        const int p = idx / H3, cc = idx - p * H3;
        const int ii = p / 3, jj = p % 3;
        float v;
        if (cc < HH)           v = wb[jj * HH + cc];
        else if (cc < 2 * HH)  v = wb[ii * HH + (cc - HH)];
        else                   v = qv[cc - 2 * HH];
        comb[idx] = v;
    }
    __syncthreads();
    float acc[9];
    const float b = gb1[o];
    #pragma unroll
    for (int p = 0; p < 9; ++p) acc[p] = b;
    const float4* w1 = reinterpret_cast<const float4*>(gW1 + (size_t)o * H3);
    for (int c4 = 0; c4 < H3 / 4; ++c4) {
        const float4 w = w1[c4];
        #pragma unroll
        for (int p = 0; p < 9; ++p) {
            const float4 x = *reinterpret_cast<const float4*>(&comb[p * H3 + c4 * 4]);
            acc[p] = fmaf(x.x, w.x, fmaf(x.y, w.y, fmaf(x.z, w.z, fmaf(x.w, w.w, acc[p]))));
        }
    }
    float* __restrict__ y1 = ws + OFF_Y1 + (size_t)n * 9 * H3;
    #pragma unroll
    for (int p = 0; p < 9; ++p) y1[p * H3 + o] = fmaxf(acc[p], 0.f);
}

// ---------------- K6b: RM layer 2 + pair-sum -> REAS ----------------
__global__ __launch_bounds__(256) void k_rm2(const float* __restrict__ gW2, const float* __restrict__ gb2,
                                             float* __restrict__ ws)
{
    __shared__ float y1s[9 * H3];
    const int n = blockIdx.x / 3, ot = blockIdx.x % 3;
    const int o = ot * 256 + threadIdx.x;
    const float* __restrict__ y1 = ws + OFF_Y1 + (size_t)n * 9 * H3;
    for (int idx = threadIdx.x; idx < 9 * H3; idx += 256) y1s[idx] = y1[idx];
    __syncthreads();
    float acc[9];
    const float b = gb2[o];
    #pragma unroll
    for (int p = 0; p < 9; ++p) acc[p] = b;
    const float4* w2 = reinterpret_cast<const float4*>(gW2 + (size_t)o * H3);
    for (int c4 = 0; c4 < H3 / 4; ++c4) {
        const float4 w = w2[c4];
        #pragma unroll
        for (int p = 0; p < 9; ++p) {
            const float4 x = *reinterpret_cast<const float4*>(&y1s[p * H3 + c4 * 4]);
            acc[p] = fmaf(x.x, w.x, fmaf(x.y, w.y, fmaf(x.z, w.z, fmaf(x.w, w.w, acc[p]))));
        }
    }
    float s = 0.f;
    #pragma unroll
    for (int p = 0; p < 9; ++p) s += fmaxf(acc[p], 0.f);
    (ws + OFF_REAS)[n * H3 + o] = s;
}

// ---------------- K7: out = reasoning @ V_w.T ; 250 blocks x 128 vocab, n split 2-way ----------
#define RST 36   // padded row stride (16B-aligned, conflict-light)
__global__ __launch_bounds__(256) void k_out(const float* __restrict__ V_w, const float* __restrict__ ws,
                                             float* __restrict__ out)
{
    __shared__ float rsT[H3 * RST];   // transposed reasoning [d][n], 110 KB
    const int tid = threadIdx.x;
    const int v = blockIdx.x * 128 + (tid & 127);
    const int nh = tid >> 7;                       // n-half: 0 -> n 0..15, 1 -> n 16..31
    for (int idx = tid; idx < NB * H3; idx += 256) {
        const int n = idx / H3, d = idx - n * H3;  // coalesced read over d
        rsT[d * RST + n] = (ws + OFF_REAS)[idx];
    }
    __syncthreads();
    float acc[16];
    #pragma unroll
    for (int i = 0; i < 16; ++i) acc[i] = 0.f;
    const float4* vw = reinterpret_cast<const float4*>(V_w + (size_t)v * H3);
    for (int d4 = 0; d4 < H3 / 4; ++d4) {
        const float4 w = vw[d4];
        #pragma unroll
        for (int dd = 0; dd < 4; ++dd) {
            const float wd = (dd == 0) ? w.x : (dd == 1) ? w.y : (dd == 2) ? w.z : w.w;
            const float* rr = &rsT[(d4 * 4 + dd) * RST + nh * 16];
            #pragma unroll
            for (int q = 0; q < 4; ++q) {
                const float4 r4 = *reinterpret_cast<const float4*>(rr + 4 * q);
                acc[4 * q + 0] = fmaf(wd, r4.x, acc[4 * q + 0]);
                acc[4 * q + 1] = fmaf(wd, r4.y, acc[4 * q + 1]);
                acc[4 * q + 2] = fmaf(wd, r4.z, acc[4 * q + 2]);
                acc[4 * q + 3] = fmaf(wd, r4.w, acc[4 * q + 3]);
            }
        }
    }
    #pragma unroll
    for (int i = 0; i < 16; ++i)
        out[(size_t)(nh * 16 + i) * VOCABN + v] = acc[i];
}

extern "C" void kernel_launch(void* const* d_in, const int* in_sizes, int n_in,
                              void* d_out, int out_size, void* d_ws, size_t ws_size,
                              hipStream_t stream)
{
    const int*   stories   = (const int*)d_in[0];
    const int*   questions = (const int*)d_in[1];
    const float* emb   = (const float*)d_in[2];
    const float* qWih  = (const float*)d_in[3];
    const float* qWhh  = (const float*)d_in[4];
    const float* qbih  = (const float*)d_in[5];
    const float* qbhh  = (const float*)d_in[6];
    const float* iWih  = (const float*)d_in[7];
    const float* iWhh  = (const float*)d_in[8];
    const float* ibih  = (const float*)d_in[9];
    const float* ibhh  = (const float*)d_in[10];
    const float* Wm    = (const float*)d_in[11];
    const float* Wo_w  = (const float*)d_in[12];
    const float* Wo_b  = (const float*)d_in[13];
    const float* ftW1  = (const float*)d_in[14];
    const float* ftb1  = (const float*)d_in[15];
    const float* ftW2  = (const float*)d_in[16];
    const float* ftb2  = (const float*)d_in[17];
    const float* gW1   = (const float*)d_in[18];
    const float* gb1   = (const float*)d_in[19];
    const float* gW2   = (const float*)d_in[20];
    const float* gb2   = (const float*)d_in[21];
    const float* V_w   = (const float*)d_in[22];
    float* ws  = (float*)d_ws;
    float* out = (float*)d_out;

    hipLaunchKernelGGL(k_gi, dim3((NPOS + NQPOS) / GIB), dim3(H3), 0, stream,
                       stories, questions, emb, iWih, qWih, ibih, ibhh, qbih, qbhh, ws);
    hipLaunchKernelGGL(k_gru5, dim3(TMN + NB), dim3(512), 0, stream,
                       iWhh, qWhh, ibhh, qbhh, ws);
    hipLaunchKernelGGL(k_ft, dim3(NB), dim3(HH), 0, stream, ws + OFF_Q, ws + OFF_OK, ftW1, ftb1, ftW2, ftb2);
    for (int hp = 0; hp < HOPSN; ++hp) {
        hipLaunchKernelGGL(k_attn, dim3(NB * HEADSN), dim3(HH), 0, stream, Wm, ws, hp);
        hipLaunchKernelGGL(k_buf, dim3(NB), dim3(HH), 0, stream, Wo_w, Wo_b, ftW1, ftb1, ftW2, ftb2, ws, hp);
    }
    hipLaunchKernelGGL(k_rm1, dim3(NB * 3), dim3(256), 0, stream, gW1, gb1, ws);
    hipLaunchKernelGGL(k_rm2, dim3(NB * 3), dim3(256), 0, stream, gW2, gb2, ws);
    hipLaunchKernelGGL(k_out, dim3(VOCABN / 128), dim3(256), 0, stream, V_w, ws, out);
}

// Round 7
// 1345.301 us; speedup vs baseline: 11.7876x; 1.1010x over previous
//
#include <hip/hip_runtime.h>
#include <cmath>

#define VOCABN 32000
#define EE 128
#define HH 256
#define H3 768
#define HOPSN 3
#define HEADSN 4
#define NB 32
#define TMN 50
#define WLENN 20
#define TQN 20
#define NPOS (NB*TMN*WLENN)     // 32000 story positions
#define NQPOS (NB*TQN)          // 640 question positions

// workspace offsets (floats)
#define OFF_MEM    0
#define OFF_Q      (OFF_MEM + NB*TMN*HH)
#define OFF_OK     (OFF_Q + NB*HH)
#define OFF_WB     (OFF_OK + NB*HH)
#define OFF_REP    (OFF_WB + NB*HOPSN*HH)
#define OFF_REAS   (OFF_REP + NB*HEADSN*HH)
#define OFF_Y1     (OFF_REAS + NB*H3)                 // [32][9][768]
#define OFF_PROJ   (OFF_Y1 + NB*9*H3)                 // [32][12][50][256] f32
#define OFF_GI     (OFF_PROJ + NB*12*TMN*HH)          // __fp16[(NPOS+NQPOS)*H3]

typedef __fp16 h2 __attribute__((ext_vector_type(2)));

__device__ __forceinline__ float sigm(float x) { return 1.f / (1.f + expf(-x)); }

__device__ __forceinline__ unsigned packh2(float x, float y) {
    h2 h = __builtin_amdgcn_cvt_pkrtz(x, y);
    return __builtin_bit_cast(unsigned, h);
}

__device__ __forceinline__ float fdot2u(unsigned a, unsigned b, float c) {
    return __builtin_amdgcn_fdot2(__builtin_bit_cast(h2, a),
                                  __builtin_bit_cast(h2, b), c, false);
}

// ---------------- K1: gi = x @ Wih.T (+folded biases) for all story+question positions ---------
#define GIB 64
__global__ __launch_bounds__(768) void k_gi(const int* __restrict__ stories,
                                            const int* __restrict__ questions,
                                            const float* __restrict__ emb,
                                            const float* __restrict__ iWih,
                                            const float* __restrict__ qWih,
                                            const float* __restrict__ ibih, const float* __restrict__ ibhh,
                                            const float* __restrict__ qbih, const float* __restrict__ qbhh,
                                            float* __restrict__ ws)
{
    __shared__ unsigned xs[GIB][EE / 2];   // 64 pos x 64 packed-f16 pairs (16 KB)
    __fp16* __restrict__ gi = (__fp16*)(ws + OFF_GI);
    const int j = threadIdx.x;             // gate row 0..767
    const bool isq = blockIdx.x >= (NPOS / GIB);
    const int pblk = isq ? (blockIdx.x - NPOS / GIB) : blockIdx.x;
    const int p0 = pblk * GIB;
    const size_t g0 = (isq ? (size_t)NPOS : 0) + (size_t)p0;
    const int* __restrict__ toks = isq ? (questions + p0) : (stories + p0);
    const float* __restrict__ Wih = isq ? qWih : iWih;
    const float* __restrict__ bih = isq ? qbih : ibih;
    const float* __restrict__ bhh = isq ? qbhh : ibhh;
    const float bias = (j < 2 * HH) ? (bih[j] + bhh[j]) : bih[j];
    unsigned wreg[EE / 2];
    const float2* wrow = reinterpret_cast<const float2*>(Wih + (size_t)j * EE);
    #pragma unroll
    for (int c = 0; c < EE / 2; ++c) {
        const float2 w2 = wrow[c];
        wreg[c] = packh2(w2.x, w2.y);
    }
    for (int idx = j; idx < GIB * (EE / 2); idx += H3) {
        const int p = idx >> 6, c = idx & 63;
        const int tok = toks[p];
        const float2 e2 = reinterpret_cast<const float2*>(emb + (size_t)tok * EE)[c];
        xs[p][c] = packh2(e2.x, e2.y);
    }
    __syncthreads();
    for (int p = 0; p < GIB; ++p) {
        const uint4* x4 = reinterpret_cast<const uint4*>(&xs[p][0]);
        float acc = bias;
        #pragma unroll
        for (int c4 = 0; c4 < 16; ++c4) {
            const uint4 xv = x4[c4];               // one ds_read_b128, wave-broadcast
            acc = fdot2u(xv.x, wreg[4 * c4 + 0], acc);
            acc = fdot2u(xv.y, wreg[4 * c4 + 1], acc);
            acc = fdot2u(xv.z, wreg[4 * c4 + 2], acc);
            acc = fdot2u(xv.w, wreg[4 * c4 + 3], acc);
        }
        gi[(g0 + p) * H3 + j] = (__fp16)acc;
    }
}

// ---------------- K2: recurrent GRUs; weights pinned in 256-VGPR budget via waves_per_eu(2,2) --
// blocks 0..49: slot chains (640 steps); blocks 50..81: question chains (20 steps)
__global__ __attribute__((amdgpu_flat_work_group_size(512, 512), amdgpu_waves_per_eu(2, 2)))
void k_gru6(
    const float* __restrict__ iWhh, const float* __restrict__ qWhh,
    const float* __restrict__ ibhh, const float* __restrict__ qbhh,
    float* __restrict__ ws)
{
    __shared__ unsigned hp32[HH / 2];      // h as 128 packed f16 pairs
    __shared__ float red[HH * 5];          // stride-5 partial exchange (2-way bank max)
    const int tid = threadIdx.x;
    const int j = tid & 255, kh = tid >> 8;      // output index, k-half (0/1)
    const int blk = blockIdx.x;
    const bool isq = blk >= TMN;
    const float* __restrict__ Whh = isq ? qWhh : iWhh;
    // thread (j,kh) holds gate rows {j, 256+j, 512+j}, k in [kh*128, kh*128+128) -> 3x64 uints
    unsigned wg0[64], wg1[64], wg2[64];
    {
        const float2* r0 = reinterpret_cast<const float2*>(Whh + (size_t)j * HH + kh * 128);
        const float2* r1 = reinterpret_cast<const float2*>(Whh + (size_t)(HH + j) * HH + kh * 128);
        const float2* r2 = reinterpret_cast<const float2*>(Whh + (size_t)(2 * HH + j) * HH + kh * 128);
        #pragma unroll
        for (int c = 0; c < 64; ++c) { const float2 a = r0[c]; wg0[c] = packh2(a.x, a.y); }
        #pragma unroll
        for (int c = 0; c < 64; ++c) { const float2 a = r1[c]; wg1[c] = packh2(a.x, a.y); }
        #pragma unroll
        for (int c = 0; c < 64; ++c) { const float2 a = r2[c]; wg2[c] = packh2(a.x, a.y); }
    }
    float bnH = 0.f, hstate = 0.f;
    if (kh == 0) bnH = (isq ? qbhh : ibhh)[2 * HH + j];
    if (tid < HH / 2) hp32[tid] = 0u;
    const __fp16* __restrict__ gib = (const __fp16*)(ws + OFF_GI)
                                     + (isq ? (size_t)NPOS * H3 : 0);
    float* __restrict__ memv = ws + OFF_MEM;
    float* __restrict__ qv   = ws + OFF_Q;
    __syncthreads();

    const int nOuter = isq ? 1 : NB;
    const int c = isq ? (blk - TMN) : blk;
    for (int n = 0; n < nOuter; ++n) {
        for (int t = 0; t < WLENN; ++t) {
            const int pos = isq ? (c * TQN + t) : ((n * TMN + c) * WLENN + t);
            float gir = 0.f, giz = 0.f, gin = 0.f;
            if (kh == 0) {     // issue early, consumed after the FMA loop
                const size_t gb = (size_t)pos * H3;
                gir = (float)gib[gb + j];
                giz = (float)gib[gb + HH + j];
                gin = (float)gib[gb + 2 * HH + j];
            }
            float a0 = 0.f, a1 = 0.f, a2 = 0.f;
            const uint4* hp4 = reinterpret_cast<const uint4*>(hp32);
            #pragma unroll
            for (int c4 = 0; c4 < 16; ++c4) {
                const uint4 hh = hp4[kh * 16 + c4];   // wave-uniform: LDS broadcast
                a0 = fdot2u(hh.x, wg0[4 * c4 + 0], a0);
                a0 = fdot2u(hh.y, wg0[4 * c4 + 1], a0);
                a0 = fdot2u(hh.z, wg0[4 * c4 + 2], a0);
                a0 = fdot2u(hh.w, wg0[4 * c4 + 3], a0);
                a1 = fdot2u(hh.x, wg1[4 * c4 + 0], a1);
                a1 = fdot2u(hh.y, wg1[4 * c4 + 1], a1);
                a1 = fdot2u(hh.z, wg1[4 * c4 + 2], a1);
                a1 = fdot2u(hh.w, wg1[4 * c4 + 3], a1);
                a2 = fdot2u(hh.x, wg2[4 * c4 + 0], a2);
                a2 = fdot2u(hh.y, wg2[4 * c4 + 1], a2);
                a2 = fdot2u(hh.z, wg2[4 * c4 + 2], a2);
                a2 = fdot2u(hh.w, wg2[4 * c4 + 3], a2);
            }
            if (kh == 1) { red[j * 5 + 0] = a0; red[j * 5 + 1] = a1; red[j * 5 + 2] = a2; }
            __syncthreads();
            if (kh == 0) {
                const float* rr = red + j * 5;
                const float r  = sigm(a0 + rr[0] + gir);
                const float z  = sigm(a1 + rr[1] + giz);
                const float nn = tanhf(gin + r * (a2 + rr[2] + bnH));
                hstate = (1.f - z) * nn + z * hstate;
                reinterpret_cast<__fp16*>(hp32)[j] = (__fp16)hstate;
                if (t == WLENN - 1) {
                    if (isq) qv[c * HH + j] = hstate;
                    else     memv[(size_t)(n * TMN + c) * HH + j] = hstate;
                }
            }
            __syncthreads();
        }
    }
}

// ---------------- K3: ft(x), one block per row ----------------
__global__ __launch_bounds__(256) void k_ft(const float* __restrict__ src, float* __restrict__ dst,
                                            const float* __restrict__ W1, const float* __restrict__ b1,
                                            const float* __restrict__ W2, const float* __restrict__ b2)
{
    __shared__ float xr[HH];
    __shared__ float y1[HH];
    const int n = blockIdx.x, j = threadIdx.x;
    xr[j] = src[n * HH + j];
    __syncthreads();
    float acc = b1[j];
    const float4* w1 = reinterpret_cast<const float4*>(W1 + j * HH);
    #pragma unroll 4
    for (int k4 = 0; k4 < HH / 4; ++k4) {
        const float4 w = w1[k4];
        const float4 x = *reinterpret_cast<const float4*>(&xr[k4 * 4]);
        acc = fmaf(x.x, w.x, fmaf(x.y, w.y, fmaf(x.z, w.z, fmaf(x.w, w.w, acc))));
    }
    y1[j] = fmaxf(acc, 0.f);
    __syncthreads();
    acc = b2[j];
    const float4* w2 = reinterpret_cast<const float4*>(W2 + j * HH);
    #pragma unroll 4
    for (int k4 = 0; k4 < HH / 4; ++k4) {
        const float4 w = w2[k4];
        const float4 x = *reinterpret_cast<const float4*>(&y1[k4 * 4]);
        acc = fmaf(x.x, w.x, fmaf(x.y, w.y, fmaf(x.z, w.z, fmaf(x.w, w.w, acc))));
    }
    dst[n * HH + j] = fmaxf(acc, 0.f);
}

// ---------------- K4: proj[n][he][t][e] = tanh(mem[n] @ Wm[he].T)  — hop-independent hoist ------
__global__ __launch_bounds__(256) void k_proj(const float* __restrict__ Wm, float* __restrict__ ws)
{
    __shared__ float mem_s[TMN][HH];   // 51.2 KB
    const int n = blockIdx.x / 12, he = blockIdx.x % 12;
    const int e = threadIdx.x;
    const float* __restrict__ memory = ws + OFF_MEM + n * TMN * HH;
    for (int idx = e; idx < TMN * HH; idx += HH)
        (&mem_s[0][0])[idx] = memory[idx];
    __syncthreads();
    float p[TMN];
    #pragma unroll
    for (int t = 0; t < TMN; ++t) p[t] = 0.f;
    const float4* wrow = reinterpret_cast<const float4*>(Wm + ((size_t)he * HH + e) * HH);
    for (int d4 = 0; d4 < HH / 4; ++d4) {
        const float4 w = wrow[d4];
        #pragma unroll
        for (int t = 0; t < TMN; ++t) {
            const float4 m = *reinterpret_cast<const float4*>(&mem_s[t][d4 * 4]);
            p[t] = fmaf(m.x, w.x, fmaf(m.y, w.y, fmaf(m.z, w.z, fmaf(m.w, w.w, p[t]))));
        }
    }
    float* __restrict__ proj = ws + OFF_PROJ + ((size_t)(n * 12 + he) * TMN) * HH;
    #pragma unroll
    for (int t = 0; t < TMN; ++t) proj[t * HH + e] = tanhf(p[t]);
}

// ---------------- K5: scores+softmax+rep for one hop; block = (n, head) ----------------
__global__ __launch_bounds__(256) void k_attn2(float* __restrict__ ws, int hp)
{
    __shared__ float wred[4][TMN];
    __shared__ float sc[TMN];
    const int n = blockIdx.x / HEADSN, hh = blockIdx.x % HEADSN;
    const int e = threadIdx.x;
    const float* __restrict__ proj = ws + OFF_PROJ + ((size_t)(n * 12 + hp * HEADSN + hh) * TMN) * HH;
    const float* __restrict__ memory = ws + OFF_MEM + n * TMN * HH;
    const float okv = (ws + OFF_OK)[n * HH + e];
    const int lane = e & 63, wv = e >> 6;
    #pragma unroll 10
    for (int t = 0; t < TMN; ++t) {
        float v = proj[t * HH + e] * okv;
        #pragma unroll
        for (int off = 32; off > 0; off >>= 1) v += __shfl_xor(v, off);
        if (lane == 0) wred[wv][t] = v;
    }
    __syncthreads();
    if (e < TMN) sc[e] = wred[0][e] + wred[1][e] + wred[2][e] + wred[3][e];
    __syncthreads();
    if (e == 0) {
        float mx = sc[0];
        for (int t = 1; t < TMN; ++t) mx = fmaxf(mx, sc[t]);
        float sum = 0.f;
        for (int t = 0; t < TMN; ++t) { const float ex = expf(sc[t] - mx); sc[t] = ex; sum += ex; }
        const float inv = 1.f / sum;
        for (int t = 0; t < TMN; ++t) sc[t] *= inv;
    }
    __syncthreads();
    float r = 0.f;
    #pragma unroll 10
    for (int t = 0; t < TMN; ++t) r = fmaf(sc[t], memory[t * HH + e], r);
    (ws + OFF_REP)[(n * HEADSN + hh) * HH + e] = r;
}

// ---------------- K6: buf = rep @ Wo_w.T + Wo_b; o_k = ft(buf) ----------------
__global__ __launch_bounds__(256) void k_buf(const float* __restrict__ Wo_w, const float* __restrict__ Wo_b,
                                             const float* __restrict__ W1, const float* __restrict__ b1,
                                             const float* __restrict__ W2, const float* __restrict__ b2,
                                             float* __restrict__ ws, int hp)
{
    __shared__ float repf[HEADSN * HH];
    __shared__ float bufs[HH];
    __shared__ float y1[HH];
    const int n = blockIdx.x, j = threadIdx.x;
    const float* __restrict__ rep = ws + OFF_REP + n * HEADSN * HH;
    for (int idx = j; idx < HEADSN * HH; idx += HH) repf[idx] = rep[idx];
    __syncthreads();
    float acc = Wo_b[hp * HH + j];
    const float4* wrow = reinterpret_cast<const float4*>(Wo_w + ((size_t)hp * HH + j) * (HEADSN * HH));
    #pragma unroll 4
    for (int c4 = 0; c4 < HEADSN * HH / 4; ++c4) {
        const float4 w = wrow[c4];
        const float4 x = *reinterpret_cast<const float4*>(&repf[c4 * 4]);
        acc = fmaf(x.x, w.x, fmaf(x.y, w.y, fmaf(x.z, w.z, fmaf(x.w, w.w, acc))));
    }
    (ws + OFF_WB)[(n * HOPSN + hp) * HH + j] = acc;
    bufs[j] = acc;
    __syncthreads();
    float a1 = b1[j];
    const float4* w1 = reinterpret_cast<const float4*>(W1 + j * HH);
    #pragma unroll 4
    for (int k4 = 0; k4 < HH / 4; ++k4) {
        const float4 w = w1[k4];
        const float4 x = *reinterpret_cast<const float4*>(&bufs[k4 * 4]);
        a1 = fmaf(x.x, w.x, fmaf(x.y, w.y, fmaf(x.z, w.z, fmaf(x.w, w.w, a1))));
    }
    y1[j] = fmaxf(a1, 0.f);
    __syncthreads();
    float a2 = b2[j];
    const float4* w2 = reinterpret_cast<const float4*>(W2 + j * HH);
    #pragma unroll 4
    for (int k4 = 0; k4 < HH / 4; ++k4) {
        const float4 w = w2[k4];
        const float4 x = *reinterpret_cast<const float4*>(&y1[k4 * 4]);
        a2 = fmaf(x.x, w.x, fmaf(x.y, w.y, fmaf(x.z, w.z, fmaf(x.w, w.w, a2))));
    }
    (ws + OFF_OK)[n * HH + j] = fmaxf(a2, 0.f);
}

// ---------------- K7a: RM layer 1 — y1[n][9][o] ; grid = 32n x 3 o-tiles ----------------
__global__ __launch_bounds__(256) void k_rm1(const float* __restrict__ gW1, const float* __restrict__ gb1,
                                             float* __restrict__ ws)
{
    __shared__ float comb[9 * H3];   // 27.6 KB
    const int n = blockIdx.x / 3, ot = blockIdx.x % 3;
    const int o = ot * 256 + threadIdx.x;
    const float* __restrict__ wb = ws + OFF_WB + n * HOPSN * HH;
    const float* __restrict__ qv = ws + OFF_Q + n * HH;
    for (int idx = threadIdx.x; idx < 9 * H3; idx += 256) {
        const int p = idx / H3, cc = idx - p * H3;
        const int ii = p / 3, jj = p % 3;
        float v;
        if (cc < HH)           v = wb[jj * HH + cc];
        else if (cc < 2 * HH)  v = wb[ii * HH + (cc - HH)];
        else                   v = qv[cc - 2 * HH];
        comb[idx] = v;
    }
    __syncthreads();
    float acc[9];
    const float b = gb1[o];
    #pragma unroll
    for (int p = 0; p < 9; ++p) acc[p] = b;
    const float4* w1 = reinterpret_cast<const float4*>(gW1 + (size_t)o * H3);
    for (int c4 = 0; c4 < H3 / 4; ++c4) {
        const float4 w = w1[c4];
        #pragma unroll
        for (int p = 0; p < 9; ++p) {
            const float4 x = *reinterpret_cast<const float4*>(&comb[p * H3 + c4 * 4]);
            acc[p] = fmaf(x.x, w.x, fmaf(x.y, w.y, fmaf(x.z, w.z, fmaf(x.w, w.w, acc[p]))));
        }
    }
    float* __restrict__ y1 = ws + OFF_Y1 + (size_t)n * 9 * H3;
    #pragma unroll
    for (int p = 0; p < 9; ++p) y1[p * H3 + o] = fmaxf(acc[p], 0.f);
}

// ---------------- K7b: RM layer 2 + pair-sum -> REAS ----------------
__global__ __launch_bounds__(256) void k_rm2(const float* __restrict__ gW2, const float* __restrict__ gb2,
                                             float* __restrict__ ws)
{
    __shared__ float y1s[9 * H3];
    const int n = blockIdx.x / 3, ot = blockIdx.x % 3;
    const int o = ot * 256 + threadIdx.x;
    const float* __restrict__ y1 = ws + OFF_Y1 + (size_t)n * 9 * H3;
    for (int idx = threadIdx.x; idx < 9 * H3; idx += 256) y1s[idx] = y1[idx];
    __syncthreads();
    float acc[9];
    const float b = gb2[o];
    #pragma unroll
    for (int p = 0; p < 9; ++p) acc[p] = b;
    const float4* w2 = reinterpret_cast<const float4*>(gW2 + (size_t)o * H3);
    for (int c4 = 0; c4 < H3 / 4; ++c4) {
        const float4 w = w2[c4];
        #pragma unroll
        for (int p = 0; p < 9; ++p) {
            const float4 x = *reinterpret_cast<const float4*>(&y1s[p * H3 + c4 * 4]);
            acc[p] = fmaf(x.x, w.x, fmaf(x.y, w.y, fmaf(x.z, w.z, fmaf(x.w, w.w, acc[p]))));
        }
    }
    float s = 0.f;
    #pragma unroll
    for (int p = 0; p < 9; ++p) s += fmaxf(acc[p], 0.f);
    (ws + OFF_REAS)[n * H3 + o] = s;
}

// ---------------- K8: out = reasoning @ V_w.T ; 250 blocks x 128 vocab, n split 2-way ----------
#define RST 36   // padded row stride (16B-aligned, conflict-light)
__global__ __launch_bounds__(256) void k_out(const float* __restrict__ V_w, const float* __restrict__ ws,
                                             float* __restrict__ out)
{
    __shared__ float rsT[H3 * RST];   // transposed reasoning [d][n], 110 KB
    const int tid = threadIdx.x;
    const int v = blockIdx.x * 128 + (tid & 127);
    const int nh = tid >> 7;                       // n-half: 0 -> n 0..15, 1 -> n 16..31
    for (int idx = tid; idx < NB * H3; idx += 256) {
        const int n = idx / H3, d = idx - n * H3;  // coalesced read over d
        rsT[d * RST + n] = (ws + OFF_REAS)[idx];
    }
    __syncthreads();
    float acc[16];
    #pragma unroll
    for (int i = 0; i < 16; ++i) acc[i] = 0.f;
    const float4* vw = reinterpret_cast<const float4*>(V_w + (size_t)v * H3);
    for (int d4 = 0; d4 < H3 / 4; ++d4) {
        const float4 w = vw[d4];
        #pragma unroll
        for (int dd = 0; dd < 4; ++dd) {
            const float wd = (dd == 0) ? w.x : (dd == 1) ? w.y : (dd == 2) ? w.z : w.w;
            const float* rr = &rsT[(d4 * 4 + dd) * RST + nh * 16];
            #pragma unroll
            for (int q = 0; q < 4; ++q) {
                const float4 r4 = *reinterpret_cast<const float4*>(rr + 4 * q);
                acc[4 * q + 0] = fmaf(wd, r4.x, acc[4 * q + 0]);
                acc[4 * q + 1] = fmaf(wd, r4.y, acc[4 * q + 1]);
                acc[4 * q + 2] = fmaf(wd, r4.z, acc[4 * q + 2]);
                acc[4 * q + 3] = fmaf(wd, r4.w, acc[4 * q + 3]);
            }
        }
    }
    #pragma unroll
    for (int i = 0; i < 16; ++i)
        out[(size_t)(nh * 16 + i) * VOCABN + v] = acc[i];
}

extern "C" void kernel_launch(void* const* d_in, const int* in_sizes, int n_in,
                              void* d_out, int out_size, void* d_ws, size_t ws_size,
                              hipStream_t stream)
{
    const int*   stories   = (const int*)d_in[0];
    const int*   questions = (const int*)d_in[1];
    const float* emb   = (const float*)d_in[2];
    const float* qWih  = (const float*)d_in[3];
    const float* qWhh  = (const float*)d_in[4];
    const float* qbih  = (const float*)d_in[5];
    const float* qbhh  = (const float*)d_in[6];
    const float* iWih  = (const float*)d_in[7];
    const float* iWhh  = (const float*)d_in[8];
    const float* ibih  = (const float*)d_in[9];
    const float* ibhh  = (const float*)d_in[10];
    const float* Wm    = (const float*)d_in[11];
    const float* Wo_w  = (const float*)d_in[12];
    const float* Wo_b  = (const float*)d_in[13];
    const float* ftW1  = (const float*)d_in[14];
    const float* ftb1  = (const float*)d_in[15];
    const float* ftW2  = (const float*)d_in[16];
    const float* ftb2  = (const float*)d_in[17];
    const float* gW1   = (const float*)d_in[18];
    const float* gb1   = (const float*)d_in[19];
    const float* gW2   = (const float*)d_in[20];
    const float* gb2   = (const float*)d_in[21];
    const float* V_w   = (const float*)d_in[22];
    float* ws  = (float*)d_ws;
    float* out = (float*)d_out;

    hipLaunchKernelGGL(k_gi, dim3((NPOS + NQPOS) / GIB), dim3(H3), 0, stream,
                       stories, questions, emb, iWih, qWih, ibih, ibhh, qbih, qbhh, ws);
    hipLaunchKernelGGL(k_gru6, dim3(TMN + NB), dim3(512), 0, stream,
                       iWhh, qWhh, ibhh, qbhh, ws);
    hipLaunchKernelGGL(k_ft, dim3(NB), dim3(HH), 0, stream, ws + OFF_Q, ws + OFF_OK, ftW1, ftb1, ftW2, ftb2);
    hipLaunchKernelGGL(k_proj, dim3(NB * 12), dim3(256), 0, stream, Wm, ws);
    for (int hp = 0; hp < HOPSN; ++hp) {
        hipLaunchKernelGGL(k_attn2, dim3(NB * HEADSN), dim3(256), 0, stream, ws, hp);
        hipLaunchKernelGGL(k_buf, dim3(NB), dim3(256), 0, stream, Wo_w, Wo_b, ftW1, ftb1, ftW2, ftb2, ws, hp);
    }
    hipLaunchKernelGGL(k_rm1, dim3(NB * 3), dim3(256), 0, stream, gW1, gb1, ws);
    hipLaunchKernelGGL(k_rm2, dim3(NB * 3), dim3(256), 0, stream, gW2, gb2, ws);
    hipLaunchKernelGGL(k_out, dim3(VOCABN / 128), dim3(256), 0, stream, V_w, ws, out);
}